// Round 6
// baseline (1276.214 us; speedup 1.0000x reference)
//
#include <hip/hip_runtime.h>

// EncoderSRNN: T=256 steps, B=128, HDIM=EDIM=256, SSZ=64, SDIM=64, SDEPTH=2, NACT=3
#define T_STEPS 256
#define BATCH 128

// ws float offsets (transposed weights + combined bias)
#define WEHT_OFF 0         // [e][h] 256x256
#define WHHT_OFF 65536     // [e][h] 256x256
#define WSHT_OFF 131072    // [j][h] 128x256
#define WHST_OFF 163840    // [e][s] 256x64
#define WSUT_OFF 180224    // [j][s] 128x64
#define BC_OFF   188416    // bc[h] = b_eh+b_hh+b_sh

#define HID_OFF   8388608
#define STACK_OFF 8421376
#define ACTS_OFF  8945664

// In-loop barrier: LDS-only fence + raw barrier (no vmcnt drain; all cross-wave
// handoffs are DS ops, all global ops in the loop are same-thread ordered).
#define BAR_LDS() do { \
    asm volatile("s_waitcnt lgkmcnt(0)" ::: "memory"); \
    __builtin_amdgcn_s_barrier(); \
} while (0)

// broadcast lane l of v to all lanes via SGPR (VALU pipe, NOT the LDS unit)
__device__ __forceinline__ float rl(float v, int l) {
    return __int_as_float(__builtin_amdgcn_readlane(__float_as_int(v), l));
}

// ---------------- kernel 0: transpose weights into ws, fold biases ----------
__global__ __launch_bounds__(256) void prep_kernel(
    const float* __restrict__ W_hh, const float* __restrict__ b_hh,
    const float* __restrict__ W_eh, const float* __restrict__ b_eh,
    const float* __restrict__ W_sh, const float* __restrict__ b_sh,
    const float* __restrict__ W_hs, const float* __restrict__ W_su,
    float* __restrict__ ws)
{
    int idx = blockIdx.x * 256 + threadIdx.x;
    if (idx < 65536) {                       // W_ehT[e][h] = W_eh[h][e]
        ws[WEHT_OFF + idx] = W_eh[(idx & 255) * 256 + (idx >> 8)];
    } else if (idx < 131072) {               // W_hhT
        int k = idx - 65536;
        ws[WHHT_OFF + k] = W_hh[(k & 255) * 256 + (k >> 8)];
    } else if (idx < 163840) {               // W_shT[j][h] = W_sh[h][j]
        int k = idx - 131072;
        ws[WSHT_OFF + k] = W_sh[(k & 255) * 128 + (k >> 8)];
    } else if (idx < 180224) {               // W_hsT[e][s] = W_hs[s][e]
        int k = idx - 163840;
        ws[WHST_OFF + k] = W_hs[(k & 63) * 256 + (k >> 6)];
    } else if (idx < 188416) {               // W_suT[j][s] = W_su[s][j]
        int k = idx - 180224;
        ws[WSUT_OFF + k] = W_su[(k & 63) * 128 + (k >> 6)];
    } else if (idx < 188672) {
        int k = idx - 188416;
        ws[BC_OFF + k] = b_eh[k] + b_hh[k] + b_sh[k];
    }
}

// ---------------- kernel 1: ex[t,b,h] = emb_W[tok]@W_eh.T + bc  -------------
__global__ __launch_bounds__(256) void ex_gemm(
    const int* __restrict__ tokens, const float* __restrict__ emb_W,
    const float* __restrict__ ws, float* __restrict__ outp)
{
    __shared__ __align__(16) float aT[64 * 40];
    __shared__ int tok[32];
    const int t = threadIdx.x;
    const int R0 = blockIdx.x * 32;
    if (t < 32) tok[t] = tokens[R0 + t];
    __syncthreads();

    float acc[32];
#pragma unroll
    for (int r = 0; r < 32; r++) acc[r] = 0.f;

    for (int e0 = 0; e0 < 256; e0 += 64) {
        {
            int r = t >> 3, seg = t & 7;
            const float* src = emb_W + (size_t)tok[r] * 256 + e0 + seg * 8;
            float4 v0 = *(const float4*)(src);
            float4 v1 = *(const float4*)(src + 4);
            int eb = seg * 8;
            aT[(eb + 0) * 40 + r] = v0.x; aT[(eb + 1) * 40 + r] = v0.y;
            aT[(eb + 2) * 40 + r] = v0.z; aT[(eb + 3) * 40 + r] = v0.w;
            aT[(eb + 4) * 40 + r] = v1.x; aT[(eb + 5) * 40 + r] = v1.y;
            aT[(eb + 6) * 40 + r] = v1.z; aT[(eb + 7) * 40 + r] = v1.w;
        }
        __syncthreads();
        const float* wp = ws + WEHT_OFF + (size_t)e0 * 256 + t;
#pragma unroll 4
        for (int e = 0; e < 64; e++) {
            float wv = wp[(size_t)e * 256];
            const float4* arow = (const float4*)&aT[e * 40];
#pragma unroll
            for (int j = 0; j < 8; j++) {
                float4 a4 = arow[j];
                acc[j * 4 + 0] = fmaf(a4.x, wv, acc[j * 4 + 0]);
                acc[j * 4 + 1] = fmaf(a4.y, wv, acc[j * 4 + 1]);
                acc[j * 4 + 2] = fmaf(a4.z, wv, acc[j * 4 + 2]);
                acc[j * 4 + 3] = fmaf(a4.w, wv, acc[j * 4 + 3]);
            }
        }
        __syncthreads();
    }
    float bcv = ws[BC_OFF + t];
#pragma unroll
    for (int r = 0; r < 32; r++)
        outp[(size_t)(R0 + r) * 256 + t] = acc[r] + bcv;
}

// ---------------- kernel 2: sequential scan, LDS-traffic-minimized ----------
// 128 blocks x 512 threads; block b = batch elem b; 2 waves/SIMD (attr), so the
// unified VGPR+AGPR budget is ~512 regs/wave. ALL per-thread weights pinned via
// empty asm(+v) (non-rematerializable -> live on-chip):
//   whh 32xfloat4=128 + wsh 16xfloat4=64 + whs 32 + wsu 16 = 240 regs/thread.
// Previous round was LDS-unit-throughput-bound (~3900cy/step of DS ops):
//   - whs/wsu now come from regs (was 96KB/step of LDS reads)
//   - hid/tops wave-slices: ONE spread ds_read_b32 (lanes 0-31 = hid slice,
//     lanes 32-47 = tops slice) + v_readlane broadcasts (VALU pipe) replace
//     12 uniform b128 reads/wave (uniform reads waste 63/64 of LDS BW).
__attribute__((amdgpu_flat_work_group_size(512, 512)))
__attribute__((amdgpu_waves_per_eu(2, 2)))
__global__ void rnn_scan(
    const float* __restrict__ ws,
    const float* __restrict__ W_ha, const float* __restrict__ b_ha,
    const float* __restrict__ W_hg, const float* __restrict__ b_hg,
    const float* __restrict__ b_hs, const float* __restrict__ b_su,
    const float* __restrict__ empty_elem,
    float* __restrict__ out)
{
    __shared__ __align__(16) float hid[256];
    __shared__ __align__(16) float tops[128];
    __shared__ __align__(16) float partial[8 * 256]; // 8 KB
    __shared__ __align__(16) float ppb[8 * 64];
    __shared__ __align__(16) float pub[8 * 64];
    __shared__ __align__(16) float bnd[16 * 64];     // old boundary rows
    __shared__ __align__(16) float whaL[1024];       // rows 0-2: W_ha, row 3: W_hg
    __shared__ float scal[4];

    const int t = threadIdx.x, lane = t & 63, w = t >> 6;
    const int b = blockIdx.x;

    // ---- weight registers (loaded once, then liveness-pinned)
    float4 whh[32], wsh[16];
    float  whs_r[32], wsu_r[16];
    {
        const float* base = ws + WHHT_OFF + (size_t)(w * 32) * 256 + lane * 4;
#pragma unroll
        for (int e = 0; e < 32; e++) whh[e] = *(const float4*)(base + (size_t)e * 256);
        const float* base2 = ws + WSHT_OFF + (size_t)(w * 16) * 256 + lane * 4;
#pragma unroll
        for (int j = 0; j < 16; j++) wsh[j] = *(const float4*)(base2 + (size_t)j * 256);
        const float* base3 = ws + WHST_OFF + (size_t)(w * 32) * 64 + lane;
#pragma unroll
        for (int e = 0; e < 32; e++) whs_r[e] = base3[(size_t)e * 64];
        const float* base4 = ws + WSUT_OFF + (size_t)(w * 16) * 64 + lane;
#pragma unroll
        for (int j = 0; j < 16; j++) wsu_r[j] = base4[(size_t)j * 64];
    }
    // pin: opaque defs -> not rematerializable -> kept live on-chip
#pragma unroll
    for (int e = 0; e < 32; e++)
        asm volatile("" : "+v"(whh[e].x), "+v"(whh[e].y), "+v"(whh[e].z), "+v"(whh[e].w));
#pragma unroll
    for (int j = 0; j < 16; j++)
        asm volatile("" : "+v"(wsh[j].x), "+v"(wsh[j].y), "+v"(wsh[j].z), "+v"(wsh[j].w));
#pragma unroll
    for (int e = 0; e < 32; e += 4)
        asm volatile("" : "+v"(whs_r[e]), "+v"(whs_r[e+1]), "+v"(whs_r[e+2]), "+v"(whs_r[e+3]));
#pragma unroll
    for (int j = 0; j < 16; j += 4)
        asm volatile("" : "+v"(wsu_r[j]), "+v"(wsu_r[j+1]), "+v"(wsu_r[j+2]), "+v"(wsu_r[j+3]));

    // per-role bias registers
    float bscal = 0.f;
    if (lane == 0 && w < 4) bscal = (w < 3) ? b_ha[w] : b_hg[0];
    float bhs_r = 0.f, bsu_r = 0.f;
    if (w == 0) { bhs_r = b_hs[lane]; bsu_r = b_su[lane]; }

    // ---- init state
    const float ev = empty_elem[lane];
    float sv[8];
#pragma unroll
    for (int k = 0; k < 8; k++) sv[k] = ev;
    if (t < 256) hid[t] = 0.f;
    if (t < 128) tops[t] = empty_elem[t & 63];
    bnd[(w * 2) * 64 + lane] = ev;
    bnd[(w * 2 + 1) * 64 + lane] = ev;
    for (int i = t; i < 1024; i += 512)
        whaL[i] = (i < 768) ? W_ha[i] : W_hg[i - 768];
    __syncthreads();   // full barrier once (drains init global loads too)

    // combined slice source: lanes 0-31 read this wave's hid slice,
    // lanes 32-47 its tops slice (48-63 duplicate; harmless). Address constant.
    const float* slice_ptr = (lane < 32) ? &hid[w * 32 + lane]
                                         : &tops[w * 16 + (lane & 15)];

    // ex double-buffer: preload step 0 (waves 4-7 own hid elem h = t-256)
    float exv = (w >= 4) ? out[(size_t)b * 256 + (t - 256)] : 0.f;

    for (int ts = 0; ts < T_STEPS; ts++) {
        // prefetch NEXT step's ex (full step of latency cover)
        float exn = 0.f;
        if (w >= 4 && ts + 1 < T_STEPS)
            exn = out[((size_t)(ts + 1) * BATCH + b) * 256 + (t - 256)];

        // halo reads: neighbors' OLD boundary rows (published last step)
        float halo_lo = (w == 0) ? 0.f : bnd[((w - 1) * 2 + 1) * 64 + lane]; // row w*8-1
        float halo_hi = (w == 7) ? 0.f : bnd[((w + 1) * 2) * 64 + lane];     // row w*8+8

        // ======== phase A: one spread LDS read, then readlane-broadcast FMAs
        float slice = *slice_ptr;   // ds_read_b32 (lanes spread -> full BW)
        float4 acc = make_float4(0.f, 0.f, 0.f, 0.f);
        float accP = 0.f, accU = 0.f;
#pragma unroll
        for (int e = 0; e < 32; e++) {
            float hv = rl(slice, e);              // hid[w*32+e] via SGPR
            acc.x = fmaf(whh[e].x, hv, acc.x);
            acc.y = fmaf(whh[e].y, hv, acc.y);
            acc.z = fmaf(whh[e].z, hv, acc.z);
            acc.w = fmaf(whh[e].w, hv, acc.w);
            accP  = fmaf(whs_r[e], hv, accP);
        }
#pragma unroll
        for (int j = 0; j < 16; j++) {
            float tv = rl(slice, 32 + j);         // tops[w*16+j] via SGPR
            acc.x = fmaf(wsh[j].x, tv, acc.x);
            acc.y = fmaf(wsh[j].y, tv, acc.y);
            acc.z = fmaf(wsh[j].z, tv, acc.z);
            acc.w = fmaf(wsh[j].w, tv, acc.w);
            accU  = fmaf(wsu_r[j], tv, accU);
        }
        *(float4*)&partial[w * 256 + lane * 4] = acc;
        ppb[w * 64 + lane] = accP;
        pub[w * 64 + lane] = accU;

        // ======== phase B: act logits + gamma dots (waves 0..3, old hid)
        if (w < 4) {
            float bd = 0.f;
#pragma unroll
            for (int k = 0; k < 4; k++)
                bd = fmaf(whaL[w * 256 + k * 64 + lane], hid[k * 64 + lane], bd);
#pragma unroll
            for (int off = 32; off > 0; off >>= 1) bd += __shfl_down(bd, off);
            if (lane == 0) scal[w] = bd + bscal;
        }
        BAR_LDS(); // s1: partials + ppb/pub + scal visible; all old-state reads done

        // ---- wave 0 alone: push/pop values (only consumed by stack row 0)
        float pvv = 0.f, uvv = 0.f;
        if (w == 0) {
            float v1 = bhs_r, v2 = bsu_r;
#pragma unroll
            for (int q = 0; q < 8; q++) v1 += ppb[q * 64 + lane];
#pragma unroll
            for (int q = 0; q < 8; q++) v2 += pub[q * 64 + lane];
            pvv = fmaxf(v1, 0.f);
            uvv = fmaxf(v2, 0.f);
        }

        // ---- hid reduce (waves 4..7 own one h each)
        if (w >= 4) {
            int h = t - 256;
            float mh = exv;
#pragma unroll
            for (int q = 0; q < 8; q++) mh += partial[q * 256 + h];
            float nh = fmaxf(mh, 0.f);
            hid[h] = nh;
            out[((size_t)ts * BATCH + b) * 256 + h] = nh;
        }

        // ---- softmax -> sharpen (fast transcendentals; all threads redundant)
        float l0 = scal[0], l1 = scal[1], l2 = scal[2], gv = scal[3];
        float eg = __expf(gv);
        float g = 1.f + ((gv > 15.f) ? gv : __logf(1.f + eg));
        float m = fmaxf(l0, fmaxf(l1, l2));
        float z = __expf(l0 - m) + __expf(l1 - m) + __expf(l2 - m);
        float lz = __logf(z);
        float s0  = __expf(g * (l0 - m - lz));
        float s1v = __expf(g * (l1 - m - lz));
        float s2v = __expf(g * (l2 - m - lz));
        float S = s0 + s1v + s2v + 1e-16f;
        float rS = __builtin_amdgcn_rcpf(S);
        float p0 = s0 * rS, p1 = s1v * rS, p2 = s2v * rS;

        if (t == 0) {
            int am = 0; float bm = s0;
            if (s1v > bm) { bm = s1v; am = 1; }
            if (s2v > bm) { bm = s2v; am = 2; }
            out[ACTS_OFF + ts * BATCH + b] = (float)am;
        }

        // ---- stack blend fully in registers
        {
            float nv[8];
            float below0 = (w == 0) ? pvv : halo_lo;     // push src for row w*8
            float pop0   = (w == 0) ? uvv : sv[1];       // pop src (row 0 gets u_val)
            nv[0] = fmaf(p0, below0, fmaf(p1, pop0, p2 * sv[0]));
#pragma unroll
            for (int k = 1; k < 7; k++)
                nv[k] = fmaf(p0, sv[k - 1], fmaf(p1, sv[k + 1], p2 * sv[k]));
            nv[7] = fmaf(p0, sv[6], fmaf(p1, halo_hi, p2 * sv[7]));
#pragma unroll
            for (int k = 0; k < 8; k++) sv[k] = nv[k];
        }
        // publish new boundary rows (next step's "old" halo) + tops
        bnd[(w * 2) * 64 + lane] = sv[0];
        bnd[(w * 2 + 1) * 64 + lane] = sv[7];
        if (w == 0) { tops[lane] = sv[0]; tops[64 + lane] = sv[1]; }

        exv = exn;
        BAR_LDS(); // s2: new hid/tops/bnd visible for next step
    }

    // ---- final hid & stack
    if (t < 256) out[HID_OFF + (size_t)b * 256 + t] = hid[t];
#pragma unroll
    for (int k = 0; k < 8; k++)
        out[STACK_OFF + (size_t)b * 4096 + (w * 8 + k) * 64 + lane] = sv[k];
}

// ---------------- launcher ---------------------------------------------------
extern "C" void kernel_launch(void* const* d_in, const int* in_sizes, int n_in,
                              void* d_out, int out_size, void* d_ws, size_t ws_size,
                              hipStream_t stream)
{
    (void)in_sizes; (void)n_in; (void)out_size; (void)ws_size;
    const int*   inputs     = (const int*)d_in[0];
    const float* emb_W      = (const float*)d_in[1];
    const float* W_hh       = (const float*)d_in[2];
    const float* b_hh       = (const float*)d_in[3];
    const float* W_eh       = (const float*)d_in[4];
    const float* b_eh       = (const float*)d_in[5];
    const float* W_ha       = (const float*)d_in[6];
    const float* b_ha       = (const float*)d_in[7];
    const float* W_hg       = (const float*)d_in[8];
    const float* b_hg       = (const float*)d_in[9];
    const float* W_hs       = (const float*)d_in[10];
    const float* b_hs       = (const float*)d_in[11];
    const float* W_sh       = (const float*)d_in[12];
    const float* b_sh       = (const float*)d_in[13];
    const float* W_su       = (const float*)d_in[14];
    const float* b_su       = (const float*)d_in[15];
    const float* empty_elem = (const float*)d_in[16];
    float* out = (float*)d_out;
    float* ws  = (float*)d_ws;

    hipLaunchKernelGGL(prep_kernel, dim3(737), dim3(256), 0, stream,
                       W_hh, b_hh, W_eh, b_eh, W_sh, b_sh, W_hs, W_su, ws);
    hipLaunchKernelGGL(ex_gemm, dim3(1024), dim3(256), 0, stream,
                       inputs, emb_W, ws, out);
    hipLaunchKernelGGL(rnn_scan, dim3(128), dim3(512), 0, stream,
                       ws, W_ha, b_ha, W_hg, b_hg, b_hs, b_su, empty_elem, out);
}

// Round 7
// 1003.388 us; speedup vs baseline: 1.2719x; 1.2719x over previous
//
#include <hip/hip_runtime.h>

// EncoderSRNN: T=256 steps, B=128, HDIM=EDIM=256, SSZ=64, SDIM=64, SDEPTH=2, NACT=3
#define T_STEPS 256
#define BATCH 128

// ws float offsets (transposed weights + combined bias)
#define WEHT_OFF 0         // [e][h] 256x256
#define WHHT_OFF 65536     // [e][h] 256x256
#define WSHT_OFF 131072    // [j][h] 128x256
#define WHST_OFF 163840    // [e][s] 256x64
#define WSUT_OFF 180224    // [j][s] 128x64
#define BC_OFF   188416    // bc[h] = b_eh+b_hh+b_sh

#define HID_OFF   8388608
#define STACK_OFF 8421376
#define ACTS_OFF  8945664

// In-loop barrier: LDS-only fence + raw barrier (no vmcnt drain; all cross-wave
// handoffs are DS ops, all global ops in the loop are same-thread ordered).
#define BAR_LDS() do { \
    asm volatile("s_waitcnt lgkmcnt(0)" ::: "memory"); \
    __builtin_amdgcn_s_barrier(); \
} while (0)

// ---------------- kernel 0: transpose weights into ws, fold biases ----------
__global__ __launch_bounds__(256) void prep_kernel(
    const float* __restrict__ W_hh, const float* __restrict__ b_hh,
    const float* __restrict__ W_eh, const float* __restrict__ b_eh,
    const float* __restrict__ W_sh, const float* __restrict__ b_sh,
    const float* __restrict__ W_hs, const float* __restrict__ W_su,
    float* __restrict__ ws)
{
    int idx = blockIdx.x * 256 + threadIdx.x;
    if (idx < 65536) {                       // W_ehT[e][h] = W_eh[h][e]
        ws[WEHT_OFF + idx] = W_eh[(idx & 255) * 256 + (idx >> 8)];
    } else if (idx < 131072) {               // W_hhT
        int k = idx - 65536;
        ws[WHHT_OFF + k] = W_hh[(k & 255) * 256 + (k >> 8)];
    } else if (idx < 163840) {               // W_shT[j][h] = W_sh[h][j]
        int k = idx - 131072;
        ws[WSHT_OFF + k] = W_sh[(k & 255) * 128 + (k >> 8)];
    } else if (idx < 180224) {               // W_hsT[e][s] = W_hs[s][e]
        int k = idx - 163840;
        ws[WHST_OFF + k] = W_hs[(k & 63) * 256 + (k >> 6)];
    } else if (idx < 188416) {               // W_suT[j][s] = W_su[s][j]
        int k = idx - 180224;
        ws[WSUT_OFF + k] = W_su[(k & 63) * 128 + (k >> 6)];
    } else if (idx < 188672) {
        int k = idx - 188416;
        ws[BC_OFF + k] = b_eh[k] + b_hh[k] + b_sh[k];
    }
}

// ---------------- kernel 1: ex[t,b,h] = emb_W[tok]@W_eh.T + bc  -------------
__global__ __launch_bounds__(256) void ex_gemm(
    const int* __restrict__ tokens, const float* __restrict__ emb_W,
    const float* __restrict__ ws, float* __restrict__ outp)
{
    __shared__ __align__(16) float aT[64 * 40];
    __shared__ int tok[32];
    const int t = threadIdx.x;
    const int R0 = blockIdx.x * 32;
    if (t < 32) tok[t] = tokens[R0 + t];
    __syncthreads();

    float acc[32];
#pragma unroll
    for (int r = 0; r < 32; r++) acc[r] = 0.f;

    for (int e0 = 0; e0 < 256; e0 += 64) {
        {
            int r = t >> 3, seg = t & 7;
            const float* src = emb_W + (size_t)tok[r] * 256 + e0 + seg * 8;
            float4 v0 = *(const float4*)(src);
            float4 v1 = *(const float4*)(src + 4);
            int eb = seg * 8;
            aT[(eb + 0) * 40 + r] = v0.x; aT[(eb + 1) * 40 + r] = v0.y;
            aT[(eb + 2) * 40 + r] = v0.z; aT[(eb + 3) * 40 + r] = v0.w;
            aT[(eb + 4) * 40 + r] = v1.x; aT[(eb + 5) * 40 + r] = v1.y;
            aT[(eb + 6) * 40 + r] = v1.z; aT[(eb + 7) * 40 + r] = v1.w;
        }
        __syncthreads();
        const float* wp = ws + WEHT_OFF + (size_t)e0 * 256 + t;
#pragma unroll 4
        for (int e = 0; e < 64; e++) {
            float wv = wp[(size_t)e * 256];
            const float4* arow = (const float4*)&aT[e * 40];
#pragma unroll
            for (int j = 0; j < 8; j++) {
                float4 a4 = arow[j];
                acc[j * 4 + 0] = fmaf(a4.x, wv, acc[j * 4 + 0]);
                acc[j * 4 + 1] = fmaf(a4.y, wv, acc[j * 4 + 1]);
                acc[j * 4 + 2] = fmaf(a4.z, wv, acc[j * 4 + 2]);
                acc[j * 4 + 3] = fmaf(a4.w, wv, acc[j * 4 + 3]);
            }
        }
        __syncthreads();
    }
    float bcv = ws[BC_OFF + t];
#pragma unroll
    for (int r = 0; r < 32; r++)
        outp[(size_t)(R0 + r) * 256 + t] = acc[r] + bcv;
}

// ---------------- kernel 2: sequential scan, 2 LDS-only barriers/step -------
// 128 blocks x 512 threads; block b = batch elem b (1 block/CU due to ~118KB
// LDS, so 2 waves/SIMD -> unified reg budget ~512/wave but the PROVEN-safe
// pin count is 192 regs/thread (r6: 240 pinned -> scratch spill, +17MB writes).
//   whh 32xfloat4=128 + wsh 16xfloat4=64 = 192 pinned via empty asm(+v)
//   whs: LDS, PACKED [(e>>2)][s][(e&3)] so phase A reads 8 spread b128/wave
//        instead of 32 b32/wave (the r5 profile's largest LDS stream)
//   wsu: LDS, packed [(j>>2)][s][(j&3)] (4 b128/wave)
//   ppb+pub merged into one float2 buffer: 1 b64 write + 8 b64 reduce reads
__attribute__((amdgpu_flat_work_group_size(512, 512)))
__attribute__((amdgpu_waves_per_eu(2, 2)))
__global__ void rnn_scan(
    const float* __restrict__ ws,
    const float* __restrict__ W_ha, const float* __restrict__ b_ha,
    const float* __restrict__ W_hg, const float* __restrict__ b_hg,
    const float* __restrict__ b_hs, const float* __restrict__ b_su,
    const float* __restrict__ empty_elem,
    float* __restrict__ out)
{
    __shared__ __align__(16) float hid[256];
    __shared__ __align__(16) float tops[128];
    __shared__ __align__(16) float partial[8 * 256]; // 8 KB
    __shared__ __align__(16) float2 pp2[8 * 64];     // 4 KB {accP, accU}
    __shared__ __align__(16) float bnd[16 * 64];     // old boundary rows
    __shared__ __align__(16) float wsu_l[8192];      // 32 KB, packed [j>>2][s][j&3]
    __shared__ __align__(16) float whs_l[16384];     // 64 KB, packed [e>>2][s][e&3]
    __shared__ __align__(16) float whaL[1024];       // rows 0-2: W_ha, row 3: W_hg
    __shared__ float scal[4];

    const int t = threadIdx.x, lane = t & 63, w = t >> 6;
    const int b = blockIdx.x;

    // ---- weight registers (loaded once, then liveness-pinned)
    float4 whh[32], wsh[16];
    {
        const float* base = ws + WHHT_OFF + (size_t)(w * 32) * 256 + lane * 4;
#pragma unroll
        for (int e = 0; e < 32; e++) whh[e] = *(const float4*)(base + (size_t)e * 256);
        const float* base2 = ws + WSHT_OFF + (size_t)(w * 16) * 256 + lane * 4;
#pragma unroll
        for (int j = 0; j < 16; j++) wsh[j] = *(const float4*)(base2 + (size_t)j * 256);
    }
    // pin: opaque defs -> not rematerializable -> kept live on-chip.
    // 192 regs pinned is the proven-safe ceiling (r6: 240 -> scratch spill).
#pragma unroll
    for (int e = 0; e < 32; e++)
        asm volatile("" : "+v"(whh[e].x), "+v"(whh[e].y), "+v"(whh[e].z), "+v"(whh[e].w));
#pragma unroll
    for (int j = 0; j < 16; j++)
        asm volatile("" : "+v"(wsh[j].x), "+v"(wsh[j].y), "+v"(wsh[j].z), "+v"(wsh[j].w));

    // per-role bias registers
    float bscal = 0.f;
    if (lane == 0 && w < 4) bscal = (w < 3) ? b_ha[w] : b_hg[0];
    float bhs_r = 0.f, bsu_r = 0.f;
    if (w == 0) { bhs_r = b_hs[lane]; bsu_r = b_su[lane]; }

    // ---- init state: stack rows in registers, weights + small state in LDS
    const float ev = empty_elem[lane];
    float sv[8];
#pragma unroll
    for (int k = 0; k < 8; k++) sv[k] = ev;
    if (t < 256) hid[t] = 0.f;
    if (t < 128) tops[t] = empty_elem[t & 63];
    bnd[(w * 2) * 64 + lane] = ev;
    bnd[(w * 2 + 1) * 64 + lane] = ev;
    // whs packed: src i = e*64+s ([e][s]) -> dst (e>>2)*256 + s*4 + (e&3)
    for (int i = t; i < 16384; i += 512)
        whs_l[(i >> 8) * 256 + (i & 63) * 4 + ((i >> 6) & 3)] = ws[WHST_OFF + i];
    for (int i = t; i < 8192; i += 512) {
        int j = i >> 6, s = i & 63;
        wsu_l[(j >> 2) * 256 + s * 4 + (j & 3)] = ws[WSUT_OFF + i];
    }
    for (int i = t; i < 1024; i += 512)
        whaL[i] = (i < 768) ? W_ha[i] : W_hg[i - 768];
    __syncthreads();   // full barrier once (drains init global loads too)

    // ex double-buffer: preload step 0 (waves 4-7 own hid elem h = t-256)
    float exv = (w >= 4) ? out[(size_t)b * 256 + (t - 256)] : 0.f;

    const float4* whs4 = (const float4*)whs_l;  // [(e>>2)*64 + s]
    const float4* wsu4 = (const float4*)wsu_l;  // [(j>>2)*64 + s]

    for (int ts = 0; ts < T_STEPS; ts++) {
        // prefetch NEXT step's ex (full step of latency cover, no vmcnt at barriers)
        float exn = 0.f;
        if (w >= 4 && ts + 1 < T_STEPS)
            exn = out[((size_t)(ts + 1) * BATCH + b) * 256 + (t - 256)];

        // halo reads: neighbors' OLD boundary rows (published last step)
        float halo_lo = (w == 0) ? 0.f : bnd[((w - 1) * 2 + 1) * 64 + lane]; // row w*8-1
        float halo_hi = (w == 7) ? 0.f : bnd[((w + 1) * 2) * 64 + lane];     // row w*8+8

        // ======== phase A: all dot-product partials from old state
        float4 acc = make_float4(0.f, 0.f, 0.f, 0.f);
        float accP = 0.f, accU = 0.f;
#pragma unroll
        for (int eb = 0; eb < 8; eb++) {
            float4 hv = *(const float4*)&hid[w * 32 + eb * 4];   // uniform b128
            float4 sp = whs4[(w * 8 + eb) * 64 + lane];          // spread b128
            acc.x = fmaf(whh[eb*4+0].x, hv.x, acc.x); acc.y = fmaf(whh[eb*4+0].y, hv.x, acc.y);
            acc.z = fmaf(whh[eb*4+0].z, hv.x, acc.z); acc.w = fmaf(whh[eb*4+0].w, hv.x, acc.w);
            acc.x = fmaf(whh[eb*4+1].x, hv.y, acc.x); acc.y = fmaf(whh[eb*4+1].y, hv.y, acc.y);
            acc.z = fmaf(whh[eb*4+1].z, hv.y, acc.z); acc.w = fmaf(whh[eb*4+1].w, hv.y, acc.w);
            acc.x = fmaf(whh[eb*4+2].x, hv.z, acc.x); acc.y = fmaf(whh[eb*4+2].y, hv.z, acc.y);
            acc.z = fmaf(whh[eb*4+2].z, hv.z, acc.z); acc.w = fmaf(whh[eb*4+2].w, hv.z, acc.w);
            acc.x = fmaf(whh[eb*4+3].x, hv.w, acc.x); acc.y = fmaf(whh[eb*4+3].y, hv.w, acc.y);
            acc.z = fmaf(whh[eb*4+3].z, hv.w, acc.z); acc.w = fmaf(whh[eb*4+3].w, hv.w, acc.w);
            accP = fmaf(sp.x, hv.x, accP);
            accP = fmaf(sp.y, hv.y, accP);
            accP = fmaf(sp.z, hv.z, accP);
            accP = fmaf(sp.w, hv.w, accP);
        }
#pragma unroll
        for (int jb = 0; jb < 4; jb++) {
            float4 tv = *(const float4*)&tops[w * 16 + jb * 4];  // uniform b128
            float4 su = wsu4[(w * 4 + jb) * 64 + lane];          // spread b128
            acc.x = fmaf(wsh[jb*4+0].x, tv.x, acc.x); acc.y = fmaf(wsh[jb*4+0].y, tv.x, acc.y);
            acc.z = fmaf(wsh[jb*4+0].z, tv.x, acc.z); acc.w = fmaf(wsh[jb*4+0].w, tv.x, acc.w);
            acc.x = fmaf(wsh[jb*4+1].x, tv.y, acc.x); acc.y = fmaf(wsh[jb*4+1].y, tv.y, acc.y);
            acc.z = fmaf(wsh[jb*4+1].z, tv.y, acc.z); acc.w = fmaf(wsh[jb*4+1].w, tv.y, acc.w);
            acc.x = fmaf(wsh[jb*4+2].x, tv.z, acc.x); acc.y = fmaf(wsh[jb*4+2].y, tv.z, acc.y);
            acc.z = fmaf(wsh[jb*4+2].z, tv.z, acc.z); acc.w = fmaf(wsh[jb*4+2].w, tv.z, acc.w);
            acc.x = fmaf(wsh[jb*4+3].x, tv.w, acc.x); acc.y = fmaf(wsh[jb*4+3].y, tv.w, acc.y);
            acc.z = fmaf(wsh[jb*4+3].z, tv.w, acc.z); acc.w = fmaf(wsh[jb*4+3].w, tv.w, acc.w);
            accU = fmaf(su.x, tv.x, accU);
            accU = fmaf(su.y, tv.y, accU);
            accU = fmaf(su.z, tv.z, accU);
            accU = fmaf(su.w, tv.w, accU);
        }
        *(float4*)&partial[w * 256 + lane * 4] = acc;
        pp2[w * 64 + lane] = make_float2(accP, accU);   // one b64 write

        // ======== phase B: act logits + gamma dots (waves 0..3, old hid)
        if (w < 4) {
            float bd = 0.f;
#pragma unroll
            for (int k = 0; k < 4; k++)
                bd = fmaf(whaL[w * 256 + k * 64 + lane], hid[k * 64 + lane], bd);
#pragma unroll
            for (int off = 32; off > 0; off >>= 1) bd += __shfl_down(bd, off);
            if (lane == 0) scal[w] = bd + bscal;
        }
        BAR_LDS(); // s1: partials + pp2 + scal visible; all old-state reads done

        // ---- wave 0 alone: push/pop values (only consumed by stack row 0)
        float pvv = 0.f, uvv = 0.f;
        if (w == 0) {
            float v1 = bhs_r, v2 = bsu_r;
#pragma unroll
            for (int q = 0; q < 8; q++) {
                float2 pq = pp2[q * 64 + lane];        // b64 reads
                v1 += pq.x; v2 += pq.y;
            }
            pvv = fmaxf(v1, 0.f);
            uvv = fmaxf(v2, 0.f);
        }

        // ---- hid reduce (waves 4..7 own one h each)
        if (w >= 4) {
            int h = t - 256;
            float mh = exv;
#pragma unroll
            for (int q = 0; q < 8; q++) mh += partial[q * 256 + h];
            float nh = fmaxf(mh, 0.f);
            hid[h] = nh;
            out[((size_t)ts * BATCH + b) * 256 + h] = nh;
        }

        // ---- softmax -> sharpen (fast transcendentals; all threads redundant)
        float l0 = scal[0], l1 = scal[1], l2 = scal[2], gv = scal[3];
        float eg = __expf(gv);
        float g = 1.f + ((gv > 15.f) ? gv : __logf(1.f + eg));
        float m = fmaxf(l0, fmaxf(l1, l2));
        float z = __expf(l0 - m) + __expf(l1 - m) + __expf(l2 - m);
        float lz = __logf(z);
        float s0  = __expf(g * (l0 - m - lz));
        float s1v = __expf(g * (l1 - m - lz));
        float s2v = __expf(g * (l2 - m - lz));
        float S = s0 + s1v + s2v + 1e-16f;
        float rS = __builtin_amdgcn_rcpf(S);
        float p0 = s0 * rS, p1 = s1v * rS, p2 = s2v * rS;

        if (t == 0) {
            int am = 0; float bm = s0;
            if (s1v > bm) { bm = s1v; am = 1; }
            if (s2v > bm) { bm = s2v; am = 2; }
            out[ACTS_OFF + ts * BATCH + b] = (float)am;
        }

        // ---- stack blend fully in registers
        {
            float nv[8];
            float below0 = (w == 0) ? pvv : halo_lo;     // push src for row w*8
            float pop0   = (w == 0) ? uvv : sv[1];       // pop src (row 0 gets u_val)
            nv[0] = fmaf(p0, below0, fmaf(p1, pop0, p2 * sv[0]));
#pragma unroll
            for (int k = 1; k < 7; k++)
                nv[k] = fmaf(p0, sv[k - 1], fmaf(p1, sv[k + 1], p2 * sv[k]));
            nv[7] = fmaf(p0, sv[6], fmaf(p1, halo_hi, p2 * sv[7]));
#pragma unroll
            for (int k = 0; k < 8; k++) sv[k] = nv[k];
        }
        // publish new boundary rows (next step's "old" halo) + tops
        bnd[(w * 2) * 64 + lane] = sv[0];
        bnd[(w * 2 + 1) * 64 + lane] = sv[7];
        if (w == 0) { tops[lane] = sv[0]; tops[64 + lane] = sv[1]; }

        exv = exn;
        BAR_LDS(); // s2: new hid/tops/bnd visible for next step
    }

    // ---- final hid & stack
    if (t < 256) out[HID_OFF + (size_t)b * 256 + t] = hid[t];
#pragma unroll
    for (int k = 0; k < 8; k++)
        out[STACK_OFF + (size_t)b * 4096 + (w * 8 + k) * 64 + lane] = sv[k];
}

// ---------------- launcher ---------------------------------------------------
extern "C" void kernel_launch(void* const* d_in, const int* in_sizes, int n_in,
                              void* d_out, int out_size, void* d_ws, size_t ws_size,
                              hipStream_t stream)
{
    (void)in_sizes; (void)n_in; (void)out_size; (void)ws_size;
    const int*   inputs     = (const int*)d_in[0];
    const float* emb_W      = (const float*)d_in[1];
    const float* W_hh       = (const float*)d_in[2];
    const float* b_hh       = (const float*)d_in[3];
    const float* W_eh       = (const float*)d_in[4];
    const float* b_eh       = (const float*)d_in[5];
    const float* W_ha       = (const float*)d_in[6];
    const float* b_ha       = (const float*)d_in[7];
    const float* W_hg       = (const float*)d_in[8];
    const float* b_hg       = (const float*)d_in[9];
    const float* W_hs       = (const float*)d_in[10];
    const float* b_hs       = (const float*)d_in[11];
    const float* W_sh       = (const float*)d_in[12];
    const float* b_sh       = (const float*)d_in[13];
    const float* W_su       = (const float*)d_in[14];
    const float* b_su       = (const float*)d_in[15];
    const float* empty_elem = (const float*)d_in[16];
    float* out = (float*)d_out;
    float* ws  = (float*)d_ws;

    hipLaunchKernelGGL(prep_kernel, dim3(737), dim3(256), 0, stream,
                       W_hh, b_hh, W_eh, b_eh, W_sh, b_sh, W_hs, W_su, ws);
    hipLaunchKernelGGL(ex_gemm, dim3(1024), dim3(256), 0, stream,
                       inputs, emb_W, ws, out);
    hipLaunchKernelGGL(rnn_scan, dim3(128), dim3(512), 0, stream,
                       ws, W_ha, b_ha, W_hg, b_hg, b_hs, b_su, empty_elem, out);
}

// Round 8
// 611.569 us; speedup vs baseline: 2.0868x; 1.6407x over previous
//
#include <hip/hip_runtime.h>

// EncoderSRNN: T=256 steps, B=128, HDIM=EDIM=256, SSZ=64, SDIM=64, SDEPTH=2, NACT=3
#define T_STEPS 256
#define BATCH 128

// ws float offsets (transposed weights + combined bias)
#define WEHT_OFF 0         // [e][h] 256x256
#define WHHT_OFF 65536     // [e][h] 256x256
#define WSHT_OFF 131072    // [j][h] 128x256
#define WHST_OFF 163840    // [e][s] 256x64
#define WSUT_OFF 180224    // [j][s] 128x64
#define BC_OFF   188416    // bc[h] = b_eh+b_hh+b_sh

#define HID_OFF   8388608
#define STACK_OFF 8421376
#define ACTS_OFF  8945664

// In-loop barrier: LDS-only fence + raw barrier (no vmcnt drain; all cross-wave
// handoffs are DS ops, all global ops in the loop are same-thread ordered).
#define BAR_LDS() do { \
    asm volatile("s_waitcnt lgkmcnt(0)" ::: "memory"); \
    __builtin_amdgcn_s_barrier(); \
} while (0)

// broadcast lane l of v to all lanes via SGPR (VALU pipe, NOT the LDS unit)
__device__ __forceinline__ float rl(float v, int l) {
    return __int_as_float(__builtin_amdgcn_readlane(__float_as_int(v), l));
}

// ---------------- kernel 0: transpose weights into ws, fold biases ----------
__global__ __launch_bounds__(256) void prep_kernel(
    const float* __restrict__ W_hh, const float* __restrict__ b_hh,
    const float* __restrict__ W_eh, const float* __restrict__ b_eh,
    const float* __restrict__ W_sh, const float* __restrict__ b_sh,
    const float* __restrict__ W_hs, const float* __restrict__ W_su,
    float* __restrict__ ws)
{
    int idx = blockIdx.x * 256 + threadIdx.x;
    if (idx < 65536) {                       // W_ehT[e][h] = W_eh[h][e]
        ws[WEHT_OFF + idx] = W_eh[(idx & 255) * 256 + (idx >> 8)];
    } else if (idx < 131072) {               // W_hhT
        int k = idx - 65536;
        ws[WHHT_OFF + k] = W_hh[(k & 255) * 256 + (k >> 8)];
    } else if (idx < 163840) {               // W_shT[j][h] = W_sh[h][j]
        int k = idx - 131072;
        ws[WSHT_OFF + k] = W_sh[(k & 255) * 128 + (k >> 8)];
    } else if (idx < 180224) {               // W_hsT[e][s] = W_hs[s][e]
        int k = idx - 163840;
        ws[WHST_OFF + k] = W_hs[(k & 63) * 256 + (k >> 6)];
    } else if (idx < 188416) {               // W_suT[j][s] = W_su[s][j]
        int k = idx - 180224;
        ws[WSUT_OFF + k] = W_su[(k & 63) * 128 + (k >> 6)];
    } else if (idx < 188672) {
        int k = idx - 188416;
        ws[BC_OFF + k] = b_eh[k] + b_hh[k] + b_sh[k];
    }
}

// ---------------- kernel 1: ex[t,b,h] = emb_W[tok]@W_eh.T + bc  -------------
__global__ __launch_bounds__(256) void ex_gemm(
    const int* __restrict__ tokens, const float* __restrict__ emb_W,
    const float* __restrict__ ws, float* __restrict__ outp)
{
    __shared__ __align__(16) float aT[64 * 40];
    __shared__ int tok[32];
    const int t = threadIdx.x;
    const int R0 = blockIdx.x * 32;
    if (t < 32) tok[t] = tokens[R0 + t];
    __syncthreads();

    float acc[32];
#pragma unroll
    for (int r = 0; r < 32; r++) acc[r] = 0.f;

    for (int e0 = 0; e0 < 256; e0 += 64) {
        {
            int r = t >> 3, seg = t & 7;
            const float* src = emb_W + (size_t)tok[r] * 256 + e0 + seg * 8;
            float4 v0 = *(const float4*)(src);
            float4 v1 = *(const float4*)(src + 4);
            int eb = seg * 8;
            aT[(eb + 0) * 40 + r] = v0.x; aT[(eb + 1) * 40 + r] = v0.y;
            aT[(eb + 2) * 40 + r] = v0.z; aT[(eb + 3) * 40 + r] = v0.w;
            aT[(eb + 4) * 40 + r] = v1.x; aT[(eb + 5) * 40 + r] = v1.y;
            aT[(eb + 6) * 40 + r] = v1.z; aT[(eb + 7) * 40 + r] = v1.w;
        }
        __syncthreads();
        const float* wp = ws + WEHT_OFF + (size_t)e0 * 256 + t;
#pragma unroll 4
        for (int e = 0; e < 64; e++) {
            float wv = wp[(size_t)e * 256];
            const float4* arow = (const float4*)&aT[e * 40];
#pragma unroll
            for (int j = 0; j < 8; j++) {
                float4 a4 = arow[j];
                acc[j * 4 + 0] = fmaf(a4.x, wv, acc[j * 4 + 0]);
                acc[j * 4 + 1] = fmaf(a4.y, wv, acc[j * 4 + 1]);
                acc[j * 4 + 2] = fmaf(a4.z, wv, acc[j * 4 + 2]);
                acc[j * 4 + 3] = fmaf(a4.w, wv, acc[j * 4 + 3]);
            }
        }
        __syncthreads();
    }
    float bcv = ws[BC_OFF + t];
#pragma unroll
    for (int r = 0; r < 32; r++)
        outp[(size_t)(R0 + r) * 256 + t] = acc[r] + bcv;
}

// ---------------- kernel 2: sequential scan, 2 LDS-only barriers/step -------
// r5 base (proven 533us) + zero-register-pressure LDS-instruction cuts.
// 128 blocks x 512 threads; 1 block/CU; 2 waves/SIMD; PROVEN-safe pin = 192
// regs/thread (r6: 240 -> spill; r7: 192 + 8 float4 temps -> spill).
//   whh 32xfloat4=128 + wsh 16xfloat4=64 = 192 pinned via empty asm(+v)
//   hid/tops phase-A input: ONE spread ds_read_b32 (lanes 0-31 hid slice,
//     32-47 tops slice) + readlane broadcasts (SGPR, VALU pipe) — replaces 12
//     uniform b128/wave (r6-proven correct; r6's regression was its 240 pins)
//   whs: LDS packed e-pairs [(e>>1)][s][(e&1)] -> 16 spread b64/wave (was 32 b32)
//   wsu: LDS packed [(j>>2)][s][(j&3)] -> 4 spread b128/wave
//   ppb+pub merged float2; scal read as one b128
__attribute__((amdgpu_flat_work_group_size(512, 512)))
__attribute__((amdgpu_waves_per_eu(2, 2)))
__global__ void rnn_scan(
    const float* __restrict__ ws,
    const float* __restrict__ W_ha, const float* __restrict__ b_ha,
    const float* __restrict__ W_hg, const float* __restrict__ b_hg,
    const float* __restrict__ b_hs, const float* __restrict__ b_su,
    const float* __restrict__ empty_elem,
    float* __restrict__ out)
{
    __shared__ __align__(16) float hid[256];
    __shared__ __align__(16) float tops[128];
    __shared__ __align__(16) float partial[8 * 256]; // 8 KB
    __shared__ __align__(16) float2 pp2[8 * 64];     // 4 KB {accP, accU}
    __shared__ __align__(16) float bnd[16 * 64];     // old boundary rows
    __shared__ __align__(16) float wsu_l[8192];      // 32 KB, packed [j>>2][s][j&3]
    __shared__ __align__(16) float whs_l[16384];     // 64 KB, packed [e>>1][s][e&1]
    __shared__ __align__(16) float whaL[1024];       // rows 0-2: W_ha, row 3: W_hg
    __shared__ __align__(16) float scal[4];

    const int t = threadIdx.x, lane = t & 63, w = t >> 6;
    const int b = blockIdx.x;

    // ---- weight registers (loaded once, then liveness-pinned)
    float4 whh[32], wsh[16];
    {
        const float* base = ws + WHHT_OFF + (size_t)(w * 32) * 256 + lane * 4;
#pragma unroll
        for (int e = 0; e < 32; e++) whh[e] = *(const float4*)(base + (size_t)e * 256);
        const float* base2 = ws + WSHT_OFF + (size_t)(w * 16) * 256 + lane * 4;
#pragma unroll
        for (int j = 0; j < 16; j++) wsh[j] = *(const float4*)(base2 + (size_t)j * 256);
    }
    // pin: opaque defs -> not rematerializable -> kept live on-chip.
#pragma unroll
    for (int e = 0; e < 32; e++)
        asm volatile("" : "+v"(whh[e].x), "+v"(whh[e].y), "+v"(whh[e].z), "+v"(whh[e].w));
#pragma unroll
    for (int j = 0; j < 16; j++)
        asm volatile("" : "+v"(wsh[j].x), "+v"(wsh[j].y), "+v"(wsh[j].z), "+v"(wsh[j].w));

    // per-role bias registers
    float bscal = 0.f;
    if (lane == 0 && w < 4) bscal = (w < 3) ? b_ha[w] : b_hg[0];
    float bhs_r = 0.f, bsu_r = 0.f;
    if (w == 0) { bhs_r = b_hs[lane]; bsu_r = b_su[lane]; }

    // ---- init state: stack rows in registers, weights + small state in LDS
    const float ev = empty_elem[lane];
    float sv[8];
#pragma unroll
    for (int k = 0; k < 8; k++) sv[k] = ev;
    if (t < 256) hid[t] = 0.f;
    if (t < 128) tops[t] = empty_elem[t & 63];
    bnd[(w * 2) * 64 + lane] = ev;
    bnd[(w * 2 + 1) * 64 + lane] = ev;
    // whs packed pairs: src i = e*64+s -> dst (e>>1)*128 + s*2 + (e&1)
    for (int i = t; i < 16384; i += 512)
        whs_l[(i >> 7) * 128 + (i & 63) * 2 + ((i >> 6) & 1)] = ws[WHST_OFF + i];
    for (int i = t; i < 8192; i += 512) {
        int j = i >> 6, s = i & 63;
        wsu_l[(j >> 2) * 256 + s * 4 + (j & 3)] = ws[WSUT_OFF + i];
    }
    for (int i = t; i < 1024; i += 512)
        whaL[i] = (i < 768) ? W_ha[i] : W_hg[i - 768];
    __syncthreads();   // full barrier once (drains init global loads too)

    // combined slice source: lanes 0-31 read this wave's hid slice,
    // lanes 32-47 its tops slice (48-63 duplicate; same-addr broadcast is free)
    const float* slice_ptr = (lane < 32) ? &hid[w * 32 + lane]
                                         : &tops[w * 16 + (lane & 15)];

    // ex double-buffer: preload step 0 (waves 4-7 own hid elem h = t-256)
    float exv = (w >= 4) ? out[(size_t)b * 256 + (t - 256)] : 0.f;

    const float2* whs2 = (const float2*)whs_l;  // [(e>>1)*64 + s]
    const float4* wsu4 = (const float4*)wsu_l;  // [(j>>2)*64 + s]

    for (int ts = 0; ts < T_STEPS; ts++) {
        // prefetch NEXT step's ex (full step of latency cover, no vmcnt at barriers)
        float exn = 0.f;
        if (w >= 4 && ts + 1 < T_STEPS)
            exn = out[((size_t)(ts + 1) * BATCH + b) * 256 + (t - 256)];

        // halo reads: neighbors' OLD boundary rows (published last step)
        float halo_lo = (w == 0) ? 0.f : bnd[((w - 1) * 2 + 1) * 64 + lane]; // row w*8-1
        float halo_hi = (w == 7) ? 0.f : bnd[((w + 1) * 2) * 64 + lane];     // row w*8+8

        // ======== phase A: 1 spread b32 (state) + 16 b64 (whs) + 4 b128 (wsu)
        float slice = *slice_ptr;   // ds_read_b32, full-BW spread
        float4 acc = make_float4(0.f, 0.f, 0.f, 0.f);
        float accP = 0.f, accU = 0.f;
#pragma unroll
        for (int k = 0; k < 16; k++) {
            float hv0 = rl(slice, 2 * k);          // hid[w*32+2k] via SGPR
            float hv1 = rl(slice, 2 * k + 1);      // hid[w*32+2k+1]
            float2 sp = whs2[(w * 16 + k) * 64 + lane];   // spread b64
            acc.x = fmaf(whh[2*k].x, hv0, acc.x);
            acc.y = fmaf(whh[2*k].y, hv0, acc.y);
            acc.z = fmaf(whh[2*k].z, hv0, acc.z);
            acc.w = fmaf(whh[2*k].w, hv0, acc.w);
            acc.x = fmaf(whh[2*k+1].x, hv1, acc.x);
            acc.y = fmaf(whh[2*k+1].y, hv1, acc.y);
            acc.z = fmaf(whh[2*k+1].z, hv1, acc.z);
            acc.w = fmaf(whh[2*k+1].w, hv1, acc.w);
            accP  = fmaf(sp.x, hv0, accP);
            accP  = fmaf(sp.y, hv1, accP);
        }
#pragma unroll
        for (int jb = 0; jb < 4; jb++) {
            float4 su = wsu4[(w * 4 + jb) * 64 + lane];   // spread b128
            float tv0 = rl(slice, 32 + 4 * jb);
            float tv1 = rl(slice, 32 + 4 * jb + 1);
            float tv2 = rl(slice, 32 + 4 * jb + 2);
            float tv3 = rl(slice, 32 + 4 * jb + 3);
            acc.x = fmaf(wsh[jb*4+0].x, tv0, acc.x);
            acc.y = fmaf(wsh[jb*4+0].y, tv0, acc.y);
            acc.z = fmaf(wsh[jb*4+0].z, tv0, acc.z);
            acc.w = fmaf(wsh[jb*4+0].w, tv0, acc.w);
            acc.x = fmaf(wsh[jb*4+1].x, tv1, acc.x);
            acc.y = fmaf(wsh[jb*4+1].y, tv1, acc.y);
            acc.z = fmaf(wsh[jb*4+1].z, tv1, acc.z);
            acc.w = fmaf(wsh[jb*4+1].w, tv1, acc.w);
            acc.x = fmaf(wsh[jb*4+2].x, tv2, acc.x);
            acc.y = fmaf(wsh[jb*4+2].y, tv2, acc.y);
            acc.z = fmaf(wsh[jb*4+2].z, tv2, acc.z);
            acc.w = fmaf(wsh[jb*4+2].w, tv2, acc.w);
            acc.x = fmaf(wsh[jb*4+3].x, tv3, acc.x);
            acc.y = fmaf(wsh[jb*4+3].y, tv3, acc.y);
            acc.z = fmaf(wsh[jb*4+3].z, tv3, acc.z);
            acc.w = fmaf(wsh[jb*4+3].w, tv3, acc.w);
            accU = fmaf(su.x, tv0, accU);
            accU = fmaf(su.y, tv1, accU);
            accU = fmaf(su.z, tv2, accU);
            accU = fmaf(su.w, tv3, accU);
        }
        *(float4*)&partial[w * 256 + lane * 4] = acc;
        pp2[w * 64 + lane] = make_float2(accP, accU);   // one b64 write

        // ======== phase B: act logits + gamma dots (waves 0..3, old hid)
        if (w < 4) {
            float bd = 0.f;
#pragma unroll
            for (int k = 0; k < 4; k++)
                bd = fmaf(whaL[w * 256 + k * 64 + lane], hid[k * 64 + lane], bd);
#pragma unroll
            for (int off = 32; off > 0; off >>= 1) bd += __shfl_down(bd, off);
            if (lane == 0) scal[w] = bd + bscal;
        }
        BAR_LDS(); // s1: partials + pp2 + scal visible; all old-state reads done

        // ---- wave 0 alone: push/pop values (only consumed by stack row 0)
        float pvv = 0.f, uvv = 0.f;
        if (w == 0) {
            float v1 = bhs_r, v2 = bsu_r;
#pragma unroll
            for (int q = 0; q < 8; q++) {
                float2 pq = pp2[q * 64 + lane];        // b64 reads
                v1 += pq.x; v2 += pq.y;
            }
            pvv = fmaxf(v1, 0.f);
            uvv = fmaxf(v2, 0.f);
        }

        // ---- hid reduce (waves 4..7 own one h each)
        if (w >= 4) {
            int h = t - 256;
            float mh = exv;
#pragma unroll
            for (int q = 0; q < 8; q++) mh += partial[q * 256 + h];
            float nh = fmaxf(mh, 0.f);
            hid[h] = nh;
            out[((size_t)ts * BATCH + b) * 256 + h] = nh;
        }

        // ---- softmax -> sharpen (fast transcendentals; all threads redundant)
        float4 sc4 = *(const float4*)scal;             // one b128
        float l0 = sc4.x, l1 = sc4.y, l2 = sc4.z, gv = sc4.w;
        float eg = __expf(gv);
        float g = 1.f + ((gv > 15.f) ? gv : __logf(1.f + eg));
        float m = fmaxf(l0, fmaxf(l1, l2));
        float z = __expf(l0 - m) + __expf(l1 - m) + __expf(l2 - m);
        float lz = __logf(z);
        float s0  = __expf(g * (l0 - m - lz));
        float s1v = __expf(g * (l1 - m - lz));
        float s2v = __expf(g * (l2 - m - lz));
        float S = s0 + s1v + s2v + 1e-16f;
        float rS = __builtin_amdgcn_rcpf(S);
        float p0 = s0 * rS, p1 = s1v * rS, p2 = s2v * rS;

        if (t == 0) {
            int am = 0; float bm = s0;
            if (s1v > bm) { bm = s1v; am = 1; }
            if (s2v > bm) { bm = s2v; am = 2; }
            out[ACTS_OFF + ts * BATCH + b] = (float)am;
        }

        // ---- stack blend fully in registers
        {
            float nv[8];
            float below0 = (w == 0) ? pvv : halo_lo;     // push src for row w*8
            float pop0   = (w == 0) ? uvv : sv[1];       // pop src (row 0 gets u_val)
            nv[0] = fmaf(p0, below0, fmaf(p1, pop0, p2 * sv[0]));
#pragma unroll
            for (int k = 1; k < 7; k++)
                nv[k] = fmaf(p0, sv[k - 1], fmaf(p1, sv[k + 1], p2 * sv[k]));
            nv[7] = fmaf(p0, sv[6], fmaf(p1, halo_hi, p2 * sv[7]));
#pragma unroll
            for (int k = 0; k < 8; k++) sv[k] = nv[k];
        }
        // publish new boundary rows (next step's "old" halo) + tops
        bnd[(w * 2) * 64 + lane] = sv[0];
        bnd[(w * 2 + 1) * 64 + lane] = sv[7];
        if (w == 0) { tops[lane] = sv[0]; tops[64 + lane] = sv[1]; }

        exv = exn;
        BAR_LDS(); // s2: new hid/tops/bnd visible for next step
    }

    // ---- final hid & stack
    if (t < 256) out[HID_OFF + (size_t)b * 256 + t] = hid[t];
#pragma unroll
    for (int k = 0; k < 8; k++)
        out[STACK_OFF + (size_t)b * 4096 + (w * 8 + k) * 64 + lane] = sv[k];
}

// ---------------- launcher ---------------------------------------------------
extern "C" void kernel_launch(void* const* d_in, const int* in_sizes, int n_in,
                              void* d_out, int out_size, void* d_ws, size_t ws_size,
                              hipStream_t stream)
{
    (void)in_sizes; (void)n_in; (void)out_size; (void)ws_size;
    const int*   inputs     = (const int*)d_in[0];
    const float* emb_W      = (const float*)d_in[1];
    const float* W_hh       = (const float*)d_in[2];
    const float* b_hh       = (const float*)d_in[3];
    const float* W_eh       = (const float*)d_in[4];
    const float* b_eh       = (const float*)d_in[5];
    const float* W_ha       = (const float*)d_in[6];
    const float* b_ha       = (const float*)d_in[7];
    const float* W_hg       = (const float*)d_in[8];
    const float* b_hg       = (const float*)d_in[9];
    const float* W_hs       = (const float*)d_in[10];
    const float* b_hs       = (const float*)d_in[11];
    const float* W_sh       = (const float*)d_in[12];
    const float* b_sh       = (const float*)d_in[13];
    const float* W_su       = (const float*)d_in[14];
    const float* b_su       = (const float*)d_in[15];
    const float* empty_elem = (const float*)d_in[16];
    float* out = (float*)d_out;
    float* ws  = (float*)d_ws;

    hipLaunchKernelGGL(prep_kernel, dim3(737), dim3(256), 0, stream,
                       W_hh, b_hh, W_eh, b_eh, W_sh, b_sh, W_hs, W_su, ws);
    hipLaunchKernelGGL(ex_gemm, dim3(1024), dim3(256), 0, stream,
                       inputs, emb_W, ws, out);
    hipLaunchKernelGGL(rnn_scan, dim3(128), dim3(512), 0, stream,
                       ws, W_ha, b_ha, W_hg, b_hg, b_hs, b_su, empty_elem, out);
}

// Round 9
// 593.854 us; speedup vs baseline: 2.1490x; 1.0298x over previous
//
#include <hip/hip_runtime.h>

// EncoderSRNN: T=256 steps, B=128, HDIM=EDIM=256, SSZ=64, SDIM=64, SDEPTH=2, NACT=3
#define T_STEPS 256
#define BATCH 128

// ws float offsets (transposed weights + combined bias)
#define WEHT_OFF 0         // [e][h] 256x256
#define WHHT_OFF 65536     // [e][h] 256x256
#define WSHT_OFF 131072    // [j][h] 128x256
#define WHST_OFF 163840    // [e][s] 256x64
#define WSUT_OFF 180224    // [j][s] 128x64
#define BC_OFF   188416    // bc[h] = b_eh+b_hh+b_sh

#define HID_OFF   8388608
#define STACK_OFF 8421376
#define ACTS_OFF  8945664

// In-loop barrier: LDS-only fence + raw barrier (no vmcnt drain; all cross-wave
// handoffs are DS ops, all global ops in the loop are same-thread ordered).
#define BAR_LDS() do { \
    asm volatile("s_waitcnt lgkmcnt(0)" ::: "memory"); \
    __builtin_amdgcn_s_barrier(); \
} while (0)

// broadcast lane l of v to all lanes via SGPR (VALU pipe, NOT the LDS unit)
__device__ __forceinline__ float rl(float v, int l) {
    return __int_as_float(__builtin_amdgcn_readlane(__float_as_int(v), l));
}

// ---------------- kernel 0: transpose weights into ws, fold biases ----------
__global__ __launch_bounds__(256) void prep_kernel(
    const float* __restrict__ W_hh, const float* __restrict__ b_hh,
    const float* __restrict__ W_eh, const float* __restrict__ b_eh,
    const float* __restrict__ W_sh, const float* __restrict__ b_sh,
    const float* __restrict__ W_hs, const float* __restrict__ W_su,
    float* __restrict__ ws)
{
    int idx = blockIdx.x * 256 + threadIdx.x;
    if (idx < 65536) {                       // W_ehT[e][h] = W_eh[h][e]
        ws[WEHT_OFF + idx] = W_eh[(idx & 255) * 256 + (idx >> 8)];
    } else if (idx < 131072) {               // W_hhT
        int k = idx - 65536;
        ws[WHHT_OFF + k] = W_hh[(k & 255) * 256 + (k >> 8)];
    } else if (idx < 163840) {               // W_shT[j][h] = W_sh[h][j]
        int k = idx - 131072;
        ws[WSHT_OFF + k] = W_sh[(k & 255) * 128 + (k >> 8)];
    } else if (idx < 180224) {               // W_hsT[e][s] = W_hs[s][e]
        int k = idx - 163840;
        ws[WHST_OFF + k] = W_hs[(k & 63) * 256 + (k >> 6)];
    } else if (idx < 188416) {               // W_suT[j][s] = W_su[s][j]
        int k = idx - 180224;
        ws[WSUT_OFF + k] = W_su[(k & 63) * 128 + (k >> 6)];
    } else if (idx < 188672) {
        int k = idx - 188416;
        ws[BC_OFF + k] = b_eh[k] + b_hh[k] + b_sh[k];
    }
}

// ---------------- kernel 1: ex[t,b,h] = emb_W[tok]@W_eh.T + bc  -------------
// v2: 8 rows x 4 cols per thread. Per e: 2 LDS b128 (emb rows, broadcast) +
// 1 coalesced global b128 (weights, L2-resident) + 32 FMA. 4x fewer DS
// instructions than v1 (v1: 8 uniform b128 per e for 1 col/thread -> the
// 16-wave/CU DS pipe was the kernel's bottleneck, ~100us for a 27us-VALU GEMM).
__global__ __launch_bounds__(256) void ex_gemm(
    const int* __restrict__ tokens, const float* __restrict__ emb_W,
    const float* __restrict__ ws, float* __restrict__ outp)
{
    __shared__ __align__(16) float aT[64 * 40];   // [e][row], stride 40
    __shared__ int tok[32];
    const int t = threadIdx.x;
    const int rg = t >> 6;         // row group: rows rg*8 .. rg*8+7
    const int c0 = (t & 63) * 4;   // 4 contiguous cols
    const int R0 = blockIdx.x * 32;
    if (t < 32) tok[t] = tokens[R0 + t];
    __syncthreads();

    float acc[8][4];
#pragma unroll
    for (int r = 0; r < 8; r++)
#pragma unroll
        for (int c = 0; c < 4; c++) acc[r][c] = 0.f;

    for (int e0 = 0; e0 < 256; e0 += 64) {
        {
            int r = t >> 3, seg = t & 7;
            const float* src = emb_W + (size_t)tok[r] * 256 + e0 + seg * 8;
            float4 v0 = *(const float4*)(src);
            float4 v1 = *(const float4*)(src + 4);
            int eb = seg * 8;
            aT[(eb + 0) * 40 + r] = v0.x; aT[(eb + 1) * 40 + r] = v0.y;
            aT[(eb + 2) * 40 + r] = v0.z; aT[(eb + 3) * 40 + r] = v0.w;
            aT[(eb + 4) * 40 + r] = v1.x; aT[(eb + 5) * 40 + r] = v1.y;
            aT[(eb + 6) * 40 + r] = v1.z; aT[(eb + 7) * 40 + r] = v1.w;
        }
        __syncthreads();
        const float* wp = ws + WEHT_OFF + (size_t)e0 * 256 + c0;
#pragma unroll 2
        for (int e = 0; e < 64; e++) {
            float4 wv = *(const float4*)(wp + (size_t)e * 256);  // coalesced, L2
            const float* ar = &aT[e * 40 + rg * 8];
            float4 a0 = *(const float4*)(ar);                    // rows rg*8..+3
            float4 a1 = *(const float4*)(ar + 4);                // rows rg*8+4..+7
            acc[0][0] = fmaf(a0.x, wv.x, acc[0][0]); acc[0][1] = fmaf(a0.x, wv.y, acc[0][1]);
            acc[0][2] = fmaf(a0.x, wv.z, acc[0][2]); acc[0][3] = fmaf(a0.x, wv.w, acc[0][3]);
            acc[1][0] = fmaf(a0.y, wv.x, acc[1][0]); acc[1][1] = fmaf(a0.y, wv.y, acc[1][1]);
            acc[1][2] = fmaf(a0.y, wv.z, acc[1][2]); acc[1][3] = fmaf(a0.y, wv.w, acc[1][3]);
            acc[2][0] = fmaf(a0.z, wv.x, acc[2][0]); acc[2][1] = fmaf(a0.z, wv.y, acc[2][1]);
            acc[2][2] = fmaf(a0.z, wv.z, acc[2][2]); acc[2][3] = fmaf(a0.z, wv.w, acc[2][3]);
            acc[3][0] = fmaf(a0.w, wv.x, acc[3][0]); acc[3][1] = fmaf(a0.w, wv.y, acc[3][1]);
            acc[3][2] = fmaf(a0.w, wv.z, acc[3][2]); acc[3][3] = fmaf(a0.w, wv.w, acc[3][3]);
            acc[4][0] = fmaf(a1.x, wv.x, acc[4][0]); acc[4][1] = fmaf(a1.x, wv.y, acc[4][1]);
            acc[4][2] = fmaf(a1.x, wv.z, acc[4][2]); acc[4][3] = fmaf(a1.x, wv.w, acc[4][3]);
            acc[5][0] = fmaf(a1.y, wv.x, acc[5][0]); acc[5][1] = fmaf(a1.y, wv.y, acc[5][1]);
            acc[5][2] = fmaf(a1.y, wv.z, acc[5][2]); acc[5][3] = fmaf(a1.y, wv.w, acc[5][3]);
            acc[6][0] = fmaf(a1.z, wv.x, acc[6][0]); acc[6][1] = fmaf(a1.z, wv.y, acc[6][1]);
            acc[6][2] = fmaf(a1.z, wv.z, acc[6][2]); acc[6][3] = fmaf(a1.z, wv.w, acc[6][3]);
            acc[7][0] = fmaf(a1.w, wv.x, acc[7][0]); acc[7][1] = fmaf(a1.w, wv.y, acc[7][1]);
            acc[7][2] = fmaf(a1.w, wv.z, acc[7][2]); acc[7][3] = fmaf(a1.w, wv.w, acc[7][3]);
        }
        __syncthreads();
    }
    float4 bc4 = *(const float4*)&ws[BC_OFF + c0];
#pragma unroll
    for (int r = 0; r < 8; r++) {
        float4 o;
        o.x = acc[r][0] + bc4.x; o.y = acc[r][1] + bc4.y;
        o.z = acc[r][2] + bc4.z; o.w = acc[r][3] + bc4.w;
        *(float4*)&outp[(size_t)(R0 + rg * 8 + r) * 256 + c0] = o;
    }
}

// ---------------- kernel 2: sequential scan, 2 LDS-only barriers/step -------
// r8 base (proven 465us, zero spill) + whs b64->b128 (r7's packing, now safe:
// loop 1's only float4 temp is sp — symmetric with loop 2's su which doesn't
// spill in r8; r7's spill came from the additional uniform-b128 hv temps that
// the readlane slice removed).
//   whh 32xfloat4=128 + wsh 16xfloat4=64 = 192 pinned via empty asm(+v)
//   state: ONE spread ds_read_b32 + readlane broadcasts (SGPR)
//   whs: LDS packed [(e>>2)][s][(e&3)] -> 8 spread b128/wave
//   wsu: LDS packed [(j>>2)][s][(j&3)] -> 4 spread b128/wave
__attribute__((amdgpu_flat_work_group_size(512, 512)))
__attribute__((amdgpu_waves_per_eu(2, 2)))
__global__ void rnn_scan(
    const float* __restrict__ ws,
    const float* __restrict__ W_ha, const float* __restrict__ b_ha,
    const float* __restrict__ W_hg, const float* __restrict__ b_hg,
    const float* __restrict__ b_hs, const float* __restrict__ b_su,
    const float* __restrict__ empty_elem,
    float* __restrict__ out)
{
    __shared__ __align__(16) float hid[256];
    __shared__ __align__(16) float tops[128];
    __shared__ __align__(16) float partial[8 * 256]; // 8 KB
    __shared__ __align__(16) float2 pp2[8 * 64];     // 4 KB {accP, accU}
    __shared__ __align__(16) float bnd[16 * 64];     // old boundary rows
    __shared__ __align__(16) float wsu_l[8192];      // 32 KB, packed [j>>2][s][j&3]
    __shared__ __align__(16) float whs_l[16384];     // 64 KB, packed [e>>2][s][e&3]
    __shared__ __align__(16) float whaL[1024];       // rows 0-2: W_ha, row 3: W_hg
    __shared__ __align__(16) float scal[4];

    const int t = threadIdx.x, lane = t & 63, w = t >> 6;
    const int b = blockIdx.x;

    // ---- weight registers (loaded once, then liveness-pinned)
    float4 whh[32], wsh[16];
    {
        const float* base = ws + WHHT_OFF + (size_t)(w * 32) * 256 + lane * 4;
#pragma unroll
        for (int e = 0; e < 32; e++) whh[e] = *(const float4*)(base + (size_t)e * 256);
        const float* base2 = ws + WSHT_OFF + (size_t)(w * 16) * 256 + lane * 4;
#pragma unroll
        for (int j = 0; j < 16; j++) wsh[j] = *(const float4*)(base2 + (size_t)j * 256);
    }
    // pin: opaque defs -> not rematerializable -> kept live on-chip.
#pragma unroll
    for (int e = 0; e < 32; e++)
        asm volatile("" : "+v"(whh[e].x), "+v"(whh[e].y), "+v"(whh[e].z), "+v"(whh[e].w));
#pragma unroll
    for (int j = 0; j < 16; j++)
        asm volatile("" : "+v"(wsh[j].x), "+v"(wsh[j].y), "+v"(wsh[j].z), "+v"(wsh[j].w));

    // per-role bias registers
    float bscal = 0.f;
    if (lane == 0 && w < 4) bscal = (w < 3) ? b_ha[w] : b_hg[0];
    float bhs_r = 0.f, bsu_r = 0.f;
    if (w == 0) { bhs_r = b_hs[lane]; bsu_r = b_su[lane]; }

    // ---- init state: stack rows in registers, weights + small state in LDS
    const float ev = empty_elem[lane];
    float sv[8];
#pragma unroll
    for (int k = 0; k < 8; k++) sv[k] = ev;
    if (t < 256) hid[t] = 0.f;
    if (t < 128) tops[t] = empty_elem[t & 63];
    bnd[(w * 2) * 64 + lane] = ev;
    bnd[(w * 2 + 1) * 64 + lane] = ev;
    // whs packed quads: src i = e*64+s -> dst (e>>2)*256 + s*4 + (e&3)
    for (int i = t; i < 16384; i += 512)
        whs_l[(i >> 8) * 256 + (i & 63) * 4 + ((i >> 6) & 3)] = ws[WHST_OFF + i];
    for (int i = t; i < 8192; i += 512) {
        int j = i >> 6, s = i & 63;
        wsu_l[(j >> 2) * 256 + s * 4 + (j & 3)] = ws[WSUT_OFF + i];
    }
    for (int i = t; i < 1024; i += 512)
        whaL[i] = (i < 768) ? W_ha[i] : W_hg[i - 768];
    __syncthreads();   // full barrier once (drains init global loads too)

    // combined slice source: lanes 0-31 read this wave's hid slice,
    // lanes 32-47 its tops slice (48-63 duplicate; same-addr broadcast is free)
    const float* slice_ptr = (lane < 32) ? &hid[w * 32 + lane]
                                         : &tops[w * 16 + (lane & 15)];

    // ex double-buffer: preload step 0 (waves 4-7 own hid elem h = t-256)
    float exv = (w >= 4) ? out[(size_t)b * 256 + (t - 256)] : 0.f;

    const float4* whs4 = (const float4*)whs_l;  // [(e>>2)*64 + s]
    const float4* wsu4 = (const float4*)wsu_l;  // [(j>>2)*64 + s]

    for (int ts = 0; ts < T_STEPS; ts++) {
        // prefetch NEXT step's ex (full step of latency cover, no vmcnt at barriers)
        float exn = 0.f;
        if (w >= 4 && ts + 1 < T_STEPS)
            exn = out[((size_t)(ts + 1) * BATCH + b) * 256 + (t - 256)];

        // halo reads: neighbors' OLD boundary rows (published last step)
        float halo_lo = (w == 0) ? 0.f : bnd[((w - 1) * 2 + 1) * 64 + lane]; // row w*8-1
        float halo_hi = (w == 7) ? 0.f : bnd[((w + 1) * 2) * 64 + lane];     // row w*8+8

        // ======== phase A: 1 spread b32 (state) + 8 b128 (whs) + 4 b128 (wsu)
        float slice = *slice_ptr;   // ds_read_b32, full-BW spread
        float4 acc = make_float4(0.f, 0.f, 0.f, 0.f);
        float accP = 0.f, accU = 0.f;
#pragma unroll
        for (int eb = 0; eb < 8; eb++) {
            float4 sp = whs4[(w * 8 + eb) * 64 + lane];   // spread b128
            float h0 = rl(slice, 4 * eb + 0);
            float h1 = rl(slice, 4 * eb + 1);
            float h2 = rl(slice, 4 * eb + 2);
            float h3 = rl(slice, 4 * eb + 3);
            acc.x = fmaf(whh[eb*4+0].x, h0, acc.x);
            acc.y = fmaf(whh[eb*4+0].y, h0, acc.y);
            acc.z = fmaf(whh[eb*4+0].z, h0, acc.z);
            acc.w = fmaf(whh[eb*4+0].w, h0, acc.w);
            acc.x = fmaf(whh[eb*4+1].x, h1, acc.x);
            acc.y = fmaf(whh[eb*4+1].y, h1, acc.y);
            acc.z = fmaf(whh[eb*4+1].z, h1, acc.z);
            acc.w = fmaf(whh[eb*4+1].w, h1, acc.w);
            acc.x = fmaf(whh[eb*4+2].x, h2, acc.x);
            acc.y = fmaf(whh[eb*4+2].y, h2, acc.y);
            acc.z = fmaf(whh[eb*4+2].z, h2, acc.z);
            acc.w = fmaf(whh[eb*4+2].w, h2, acc.w);
            acc.x = fmaf(whh[eb*4+3].x, h3, acc.x);
            acc.y = fmaf(whh[eb*4+3].y, h3, acc.y);
            acc.z = fmaf(whh[eb*4+3].z, h3, acc.z);
            acc.w = fmaf(whh[eb*4+3].w, h3, acc.w);
            accP = fmaf(sp.x, h0, accP);
            accP = fmaf(sp.y, h1, accP);
            accP = fmaf(sp.z, h2, accP);
            accP = fmaf(sp.w, h3, accP);
        }
#pragma unroll
        for (int jb = 0; jb < 4; jb++) {
            float4 su = wsu4[(w * 4 + jb) * 64 + lane];   // spread b128
            float tv0 = rl(slice, 32 + 4 * jb);
            float tv1 = rl(slice, 32 + 4 * jb + 1);
            float tv2 = rl(slice, 32 + 4 * jb + 2);
            float tv3 = rl(slice, 32 + 4 * jb + 3);
            acc.x = fmaf(wsh[jb*4+0].x, tv0, acc.x);
            acc.y = fmaf(wsh[jb*4+0].y, tv0, acc.y);
            acc.z = fmaf(wsh[jb*4+0].z, tv0, acc.z);
            acc.w = fmaf(wsh[jb*4+0].w, tv0, acc.w);
            acc.x = fmaf(wsh[jb*4+1].x, tv1, acc.x);
            acc.y = fmaf(wsh[jb*4+1].y, tv1, acc.y);
            acc.z = fmaf(wsh[jb*4+1].z, tv1, acc.z);
            acc.w = fmaf(wsh[jb*4+1].w, tv1, acc.w);
            acc.x = fmaf(wsh[jb*4+2].x, tv2, acc.x);
            acc.y = fmaf(wsh[jb*4+2].y, tv2, acc.y);
            acc.z = fmaf(wsh[jb*4+2].z, tv2, acc.z);
            acc.w = fmaf(wsh[jb*4+2].w, tv2, acc.w);
            acc.x = fmaf(wsh[jb*4+3].x, tv3, acc.x);
            acc.y = fmaf(wsh[jb*4+3].y, tv3, acc.y);
            acc.z = fmaf(wsh[jb*4+3].z, tv3, acc.z);
            acc.w = fmaf(wsh[jb*4+3].w, tv3, acc.w);
            accU = fmaf(su.x, tv0, accU);
            accU = fmaf(su.y, tv1, accU);
            accU = fmaf(su.z, tv2, accU);
            accU = fmaf(su.w, tv3, accU);
        }
        *(float4*)&partial[w * 256 + lane * 4] = acc;
        pp2[w * 64 + lane] = make_float2(accP, accU);   // one b64 write

        // ======== phase B: act logits + gamma dots (waves 0..3, old hid)
        if (w < 4) {
            float bd = 0.f;
#pragma unroll
            for (int k = 0; k < 4; k++)
                bd = fmaf(whaL[w * 256 + k * 64 + lane], hid[k * 64 + lane], bd);
#pragma unroll
            for (int off = 32; off > 0; off >>= 1) bd += __shfl_down(bd, off);
            if (lane == 0) scal[w] = bd + bscal;
        }
        BAR_LDS(); // s1: partials + pp2 + scal visible; all old-state reads done

        // ---- wave 0 alone: push/pop values (only consumed by stack row 0)
        float pvv = 0.f, uvv = 0.f;
        if (w == 0) {
            float v1 = bhs_r, v2 = bsu_r;
#pragma unroll
            for (int q = 0; q < 8; q++) {
                float2 pq = pp2[q * 64 + lane];        // b64 reads
                v1 += pq.x; v2 += pq.y;
            }
            pvv = fmaxf(v1, 0.f);
            uvv = fmaxf(v2, 0.f);
        }

        // ---- hid reduce (waves 4..7 own one h each)
        if (w >= 4) {
            int h = t - 256;
            float mh = exv;
#pragma unroll
            for (int q = 0; q < 8; q++) mh += partial[q * 256 + h];
            float nh = fmaxf(mh, 0.f);
            hid[h] = nh;
            out[((size_t)ts * BATCH + b) * 256 + h] = nh;
        }

        // ---- softmax -> sharpen (fast transcendentals; all threads redundant)
        float4 sc4 = *(const float4*)scal;             // one b128
        float l0 = sc4.x, l1 = sc4.y, l2 = sc4.z, gv = sc4.w;
        float eg = __expf(gv);
        float g = 1.f + ((gv > 15.f) ? gv : __logf(1.f + eg));
        float m = fmaxf(l0, fmaxf(l1, l2));
        float z = __expf(l0 - m) + __expf(l1 - m) + __expf(l2 - m);
        float lz = __logf(z);
        float s0  = __expf(g * (l0 - m - lz));
        float s1v = __expf(g * (l1 - m - lz));
        float s2v = __expf(g * (l2 - m - lz));
        float S = s0 + s1v + s2v + 1e-16f;
        float rS = __builtin_amdgcn_rcpf(S);
        float p0 = s0 * rS, p1 = s1v * rS, p2 = s2v * rS;

        if (t == 0) {
            int am = 0; float bm = s0;
            if (s1v > bm) { bm = s1v; am = 1; }
            if (s2v > bm) { bm = s2v; am = 2; }
            out[ACTS_OFF + ts * BATCH + b] = (float)am;
        }

        // ---- stack blend fully in registers
        {
            float nv[8];
            float below0 = (w == 0) ? pvv : halo_lo;     // push src for row w*8
            float pop0   = (w == 0) ? uvv : sv[1];       // pop src (row 0 gets u_val)
            nv[0] = fmaf(p0, below0, fmaf(p1, pop0, p2 * sv[0]));
#pragma unroll
            for (int k = 1; k < 7; k++)
                nv[k] = fmaf(p0, sv[k - 1], fmaf(p1, sv[k + 1], p2 * sv[k]));
            nv[7] = fmaf(p0, sv[6], fmaf(p1, halo_hi, p2 * sv[7]));
#pragma unroll
            for (int k = 0; k < 8; k++) sv[k] = nv[k];
        }
        // publish new boundary rows (next step's "old" halo) + tops
        bnd[(w * 2) * 64 + lane] = sv[0];
        bnd[(w * 2 + 1) * 64 + lane] = sv[7];
        if (w == 0) { tops[lane] = sv[0]; tops[64 + lane] = sv[1]; }

        exv = exn;
        BAR_LDS(); // s2: new hid/tops/bnd visible for next step
    }

    // ---- final hid & stack
    if (t < 256) out[HID_OFF + (size_t)b * 256 + t] = hid[t];
#pragma unroll
    for (int k = 0; k < 8; k++)
        out[STACK_OFF + (size_t)b * 4096 + (w * 8 + k) * 64 + lane] = sv[k];
}

// ---------------- launcher ---------------------------------------------------
extern "C" void kernel_launch(void* const* d_in, const int* in_sizes, int n_in,
                              void* d_out, int out_size, void* d_ws, size_t ws_size,
                              hipStream_t stream)
{
    (void)in_sizes; (void)n_in; (void)out_size; (void)ws_size;
    const int*   inputs     = (const int*)d_in[0];
    const float* emb_W      = (const float*)d_in[1];
    const float* W_hh       = (const float*)d_in[2];
    const float* b_hh       = (const float*)d_in[3];
    const float* W_eh       = (const float*)d_in[4];
    const float* b_eh       = (const float*)d_in[5];
    const float* W_ha       = (const float*)d_in[6];
    const float* b_ha       = (const float*)d_in[7];
    const float* W_hg       = (const float*)d_in[8];
    const float* b_hg       = (const float*)d_in[9];
    const float* W_hs       = (const float*)d_in[10];
    const float* b_hs       = (const float*)d_in[11];
    const float* W_sh       = (const float*)d_in[12];
    const float* b_sh       = (const float*)d_in[13];
    const float* W_su       = (const float*)d_in[14];
    const float* b_su       = (const float*)d_in[15];
    const float* empty_elem = (const float*)d_in[16];
    float* out = (float*)d_out;
    float* ws  = (float*)d_ws;

    hipLaunchKernelGGL(prep_kernel, dim3(737), dim3(256), 0, stream,
                       W_hh, b_hh, W_eh, b_eh, W_sh, b_sh, W_hs, W_su, ws);
    hipLaunchKernelGGL(ex_gemm, dim3(1024), dim3(256), 0, stream,
                       inputs, emb_W, ws, out);
    hipLaunchKernelGGL(rnn_scan, dim3(128), dim3(512), 0, stream,
                       ws, W_ha, b_ha, W_hg, b_hg, b_hs, b_su, empty_elem, out);
}

// Round 11
// 572.553 us; speedup vs baseline: 2.2290x; 1.0372x over previous
//
#include <hip/hip_runtime.h>

// EncoderSRNN: T=256 steps, B=128, HDIM=EDIM=256, SSZ=64, SDIM=64, SDEPTH=2, NACT=3
#define T_STEPS 256
#define BATCH 128

// ws float offsets (transposed weights + combined bias)
#define WEHT_OFF 0         // [e][h] 256x256
#define WHHT_OFF 65536     // [e][h] 256x256
#define WSHT_OFF 131072    // [j][h] 128x256
#define WHST_OFF 163840    // [e][s] 256x64
#define WSUT_OFF 180224    // [j][s] 128x64
#define BC_OFF   188416    // bc[h] = b_eh+b_hh+b_sh

#define HID_OFF   8388608
#define STACK_OFF 8421376
#define ACTS_OFF  8945664

typedef __attribute__((ext_vector_type(2))) float f32x2;

// In-loop barrier: LDS-only fence + raw barrier (no vmcnt drain; all cross-wave
// handoffs are DS ops, all global ops in the loop are same-thread ordered).
#define BAR_LDS() do { \
    asm volatile("s_waitcnt lgkmcnt(0)" ::: "memory"); \
    __builtin_amdgcn_s_barrier(); \
} while (0)

// broadcast lane l of v to all lanes via SGPR (VALU pipe, NOT the LDS unit)
__device__ __forceinline__ float rl(float v, int l) {
    return __int_as_float(__builtin_amdgcn_readlane(__float_as_int(v), l));
}

// ---------------- kernel 0: transpose weights into ws, fold biases ----------
__global__ __launch_bounds__(256) void prep_kernel(
    const float* __restrict__ W_hh, const float* __restrict__ b_hh,
    const float* __restrict__ W_eh, const float* __restrict__ b_eh,
    const float* __restrict__ W_sh, const float* __restrict__ b_sh,
    const float* __restrict__ W_hs, const float* __restrict__ W_su,
    float* __restrict__ ws)
{
    int idx = blockIdx.x * 256 + threadIdx.x;
    if (idx < 65536) {                       // W_ehT[e][h] = W_eh[h][e]
        ws[WEHT_OFF + idx] = W_eh[(idx & 255) * 256 + (idx >> 8)];
    } else if (idx < 131072) {               // W_hhT
        int k = idx - 65536;
        ws[WHHT_OFF + k] = W_hh[(k & 255) * 256 + (k >> 8)];
    } else if (idx < 163840) {               // W_shT[j][h] = W_sh[h][j]
        int k = idx - 131072;
        ws[WSHT_OFF + k] = W_sh[(k & 255) * 128 + (k >> 8)];
    } else if (idx < 180224) {               // W_hsT[e][s] = W_hs[s][e]
        int k = idx - 163840;
        ws[WHST_OFF + k] = W_hs[(k & 63) * 256 + (k >> 6)];
    } else if (idx < 188416) {               // W_suT[j][s] = W_su[s][j]
        int k = idx - 180224;
        ws[WSUT_OFF + k] = W_su[(k & 63) * 128 + (k >> 6)];
    } else if (idx < 188672) {
        int k = idx - 188416;
        ws[BC_OFF + k] = b_eh[k] + b_hh[k] + b_sh[k];
    }
}

// ---------------- kernel 1: ex[t,b,h] = emb_W[tok]@W_eh.T + bc  -------------
// v3: LDS-FREE. Within a wave rg is uniform -> all 64 lanes share the same 8
// emb rows. Lane l holds emb[row][e0+l] in 8 regs (coalesced global loads);
// the per-e broadcast is readlane (SGPR/VALU pipe). v2 was DS-pipe-bound
// (512 LDS b128/thread ~ 41us of LDS issue vs 27us VALU floor); v3 has ZERO
// LDS traffic and no in-loop barriers. Packed pk_fma halves the FMA stream.
__global__ __launch_bounds__(256) void ex_gemm(
    const int* __restrict__ tokens, const float* __restrict__ emb_W,
    const float* __restrict__ ws, float* __restrict__ outp)
{
    __shared__ int tok[32];
    const int t = threadIdx.x, lane = t & 63, rg = t >> 6;
    const int c0 = lane * 4;
    const int R0 = blockIdx.x * 32;
    if (t < 32) tok[t] = tokens[R0 + t];
    __syncthreads();
    int tr[8];
#pragma unroll
    for (int r = 0; r < 8; r++) tr[r] = tok[rg * 8 + r];

    f32x2 accA[8], accB[8];
#pragma unroll
    for (int r = 0; r < 8; r++) {
        accA[r] = (f32x2){0.f, 0.f};
        accB[r] = (f32x2){0.f, 0.f};
    }

    for (int e0 = 0; e0 < 256; e0 += 64) {
        float er[8];
#pragma unroll
        for (int r = 0; r < 8; r++)
            er[r] = emb_W[(size_t)tr[r] * 256 + e0 + lane];   // coalesced
        const float* wp = ws + WEHT_OFF + (size_t)e0 * 256 + c0;
#pragma unroll
        for (int e = 0; e < 64; e++) {
            float4 wv = *(const float4*)(wp + (size_t)e * 256);  // coalesced, L2
            f32x2 w01 = {wv.x, wv.y}, w23 = {wv.z, wv.w};
#pragma unroll
            for (int r = 0; r < 8; r++) {
                float a = rl(er[r], e);
                f32x2 av = {a, a};
                accA[r] = __builtin_elementwise_fma(w01, av, accA[r]);
                accB[r] = __builtin_elementwise_fma(w23, av, accB[r]);
            }
        }
    }
    float4 bc4 = *(const float4*)&ws[BC_OFF + c0];
#pragma unroll
    for (int r = 0; r < 8; r++) {
        float4 o;
        o.x = accA[r].x + bc4.x; o.y = accA[r].y + bc4.y;
        o.z = accB[r].x + bc4.z; o.w = accB[r].y + bc4.w;
        *(float4*)&outp[(size_t)(R0 + rg * 8 + r) * 256 + c0] = o;
    }
}

// ---------------- kernel 2: sequential scan, 2 LDS-only barriers/step -------
// r9 base (proven 467us, zero spill) with whh/wsh stored as PAIR-ALIGNED f32x2
// (same 192 pinned regs, now even-aligned pairs) so the dominant FMA stream
// compiles to v_pk_fma_f32 (CDNA4 packed fp32 = 2x rate; scalar fma is half
// peak). Numerics identical (same per-component fma sequence).
//   whh2 64xf32x2=128 + wsh2 32xf32x2=64 = 192 pinned via empty asm(+v)
//   state: ONE spread ds_read_b32 + readlane broadcasts (SGPR)
//   whs: LDS packed [(e>>2)][s][(e&3)] -> 8 spread b128/wave
//   wsu: LDS packed [(j>>2)][s][(j&3)] -> 4 spread b128/wave
__attribute__((amdgpu_flat_work_group_size(512, 512)))
__attribute__((amdgpu_waves_per_eu(2, 2)))
__global__ void rnn_scan(
    const float* __restrict__ ws,
    const float* __restrict__ W_ha, const float* __restrict__ b_ha,
    const float* __restrict__ W_hg, const float* __restrict__ b_hg,
    const float* __restrict__ b_hs, const float* __restrict__ b_su,
    const float* __restrict__ empty_elem,
    float* __restrict__ out)
{
    __shared__ __align__(16) float hid[256];
    __shared__ __align__(16) float tops[128];
    __shared__ __align__(16) float partial[8 * 256]; // 8 KB
    __shared__ __align__(16) float2 pp2[8 * 64];     // 4 KB {accP, accU}
    __shared__ __align__(16) float bnd[16 * 64];     // old boundary rows
    __shared__ __align__(16) float wsu_l[8192];      // 32 KB, packed [j>>2][s][j&3]
    __shared__ __align__(16) float whs_l[16384];     // 64 KB, packed [e>>2][s][e&3]
    __shared__ __align__(16) float whaL[1024];       // rows 0-2: W_ha, row 3: W_hg
    __shared__ __align__(16) float scal[4];

    const int t = threadIdx.x, lane = t & 63, w = t >> 6;
    const int b = blockIdx.x;

    // ---- weight registers as aligned pairs (loaded once, liveness-pinned)
    f32x2 whh2[64], wsh2[32];
    {
        const float* base = ws + WHHT_OFF + (size_t)(w * 32) * 256 + lane * 4;
#pragma unroll
        for (int e = 0; e < 32; e++) {
            float4 v = *(const float4*)(base + (size_t)e * 256);
            whh2[2 * e]     = (f32x2){v.x, v.y};
            whh2[2 * e + 1] = (f32x2){v.z, v.w};
        }
        const float* base2 = ws + WSHT_OFF + (size_t)(w * 16) * 256 + lane * 4;
#pragma unroll
        for (int j = 0; j < 16; j++) {
            float4 v = *(const float4*)(base2 + (size_t)j * 256);
            wsh2[2 * j]     = (f32x2){v.x, v.y};
            wsh2[2 * j + 1] = (f32x2){v.z, v.w};
        }
    }
    // pin: opaque 64-bit defs -> not rematerializable, pair-aligned, live on-chip
#pragma unroll
    for (int i = 0; i < 64; i++) asm volatile("" : "+v"(whh2[i]));
#pragma unroll
    for (int i = 0; i < 32; i++) asm volatile("" : "+v"(wsh2[i]));

    // per-role bias registers
    float bscal = 0.f;
    if (lane == 0 && w < 4) bscal = (w < 3) ? b_ha[w] : b_hg[0];
    float bhs_r = 0.f, bsu_r = 0.f;
    if (w == 0) { bhs_r = b_hs[lane]; bsu_r = b_su[lane]; }

    // ---- init state: stack rows in registers, weights + small state in LDS
    const float ev = empty_elem[lane];
    float sv[8];
#pragma unroll
    for (int k = 0; k < 8; k++) sv[k] = ev;
    if (t < 256) hid[t] = 0.f;
    if (t < 128) tops[t] = empty_elem[t & 63];
    bnd[(w * 2) * 64 + lane] = ev;
    bnd[(w * 2 + 1) * 64 + lane] = ev;
    // whs packed quads: src i = e*64+s -> dst (e>>2)*256 + s*4 + (e&3)
    for (int i = t; i < 16384; i += 512)
        whs_l[(i >> 8) * 256 + (i & 63) * 4 + ((i >> 6) & 3)] = ws[WHST_OFF + i];
    for (int i = t; i < 8192; i += 512) {
        int j = i >> 6, s = i & 63;
        wsu_l[(j >> 2) * 256 + s * 4 + (j & 3)] = ws[WSUT_OFF + i];
    }
    for (int i = t; i < 1024; i += 512)
        whaL[i] = (i < 768) ? W_ha[i] : W_hg[i - 768];
    __syncthreads();   // full barrier once (drains init global loads too)

    // combined slice source: lanes 0-31 read this wave's hid slice,
    // lanes 32-47 its tops slice (48-63 duplicate; same-addr broadcast is free)
    const float* slice_ptr = (lane < 32) ? &hid[w * 32 + lane]
                                         : &tops[w * 16 + (lane & 15)];

    // ex double-buffer: preload step 0 (waves 4-7 own hid elem h = t-256)
    float exv = (w >= 4) ? out[(size_t)b * 256 + (t - 256)] : 0.f;

    const float4* whs4 = (const float4*)whs_l;  // [(e>>2)*64 + s]
    const float4* wsu4 = (const float4*)wsu_l;  // [(j>>2)*64 + s]

    for (int ts = 0; ts < T_STEPS; ts++) {
        // prefetch NEXT step's ex (full step of latency cover, no vmcnt at barriers)
        float exn = 0.f;
        if (w >= 4 && ts + 1 < T_STEPS)
            exn = out[((size_t)(ts + 1) * BATCH + b) * 256 + (t - 256)];

        // halo reads: neighbors' OLD boundary rows (published last step)
        float halo_lo = (w == 0) ? 0.f : bnd[((w - 1) * 2 + 1) * 64 + lane]; // row w*8-1
        float halo_hi = (w == 7) ? 0.f : bnd[((w + 1) * 2) * 64 + lane];     // row w*8+8

        // ======== phase A: 1 spread b32 (state) + 8 b128 (whs) + 4 b128 (wsu)
        float slice = *slice_ptr;   // ds_read_b32, full-BW spread
        f32x2 acc01 = (f32x2){0.f, 0.f}, acc23 = (f32x2){0.f, 0.f};
        float accP = 0.f, accU = 0.f;
#pragma unroll
        for (int eb = 0; eb < 8; eb++) {
            float4 sp = whs4[(w * 8 + eb) * 64 + lane];   // spread b128
            float h0 = rl(slice, 4 * eb + 0);
            float h1 = rl(slice, 4 * eb + 1);
            float h2 = rl(slice, 4 * eb + 2);
            float h3 = rl(slice, 4 * eb + 3);
            f32x2 h0v = {h0, h0}, h1v = {h1, h1}, h2v = {h2, h2}, h3v = {h3, h3};
            acc01 = __builtin_elementwise_fma(whh2[(4*eb+0)*2],   h0v, acc01);
            acc23 = __builtin_elementwise_fma(whh2[(4*eb+0)*2+1], h0v, acc23);
            acc01 = __builtin_elementwise_fma(whh2[(4*eb+1)*2],   h1v, acc01);
            acc23 = __builtin_elementwise_fma(whh2[(4*eb+1)*2+1], h1v, acc23);
            acc01 = __builtin_elementwise_fma(whh2[(4*eb+2)*2],   h2v, acc01);
            acc23 = __builtin_elementwise_fma(whh2[(4*eb+2)*2+1], h2v, acc23);
            acc01 = __builtin_elementwise_fma(whh2[(4*eb+3)*2],   h3v, acc01);
            acc23 = __builtin_elementwise_fma(whh2[(4*eb+3)*2+1], h3v, acc23);
            accP = fmaf(sp.x, h0, accP);
            accP = fmaf(sp.y, h1, accP);
            accP = fmaf(sp.z, h2, accP);
            accP = fmaf(sp.w, h3, accP);
        }
#pragma unroll
        for (int jb = 0; jb < 4; jb++) {
            float4 su = wsu4[(w * 4 + jb) * 64 + lane];   // spread b128
            float tv0 = rl(slice, 32 + 4 * jb);
            float tv1 = rl(slice, 32 + 4 * jb + 1);
            float tv2 = rl(slice, 32 + 4 * jb + 2);
            float tv3 = rl(slice, 32 + 4 * jb + 3);
            f32x2 t0v = {tv0, tv0}, t1v = {tv1, tv1}, t2v = {tv2, tv2}, t3v = {tv3, tv3};
            acc01 = __builtin_elementwise_fma(wsh2[(4*jb+0)*2],   t0v, acc01);
            acc23 = __builtin_elementwise_fma(wsh2[(4*jb+0)*2+1], t0v, acc23);
            acc01 = __builtin_elementwise_fma(wsh2[(4*jb+1)*2],   t1v, acc01);
            acc23 = __builtin_elementwise_fma(wsh2[(4*jb+1)*2+1], t1v, acc23);
            acc01 = __builtin_elementwise_fma(wsh2[(4*jb+2)*2],   t2v, acc01);
            acc23 = __builtin_elementwise_fma(wsh2[(4*jb+2)*2+1], t2v, acc23);
            acc01 = __builtin_elementwise_fma(wsh2[(4*jb+3)*2],   t3v, acc01);
            acc23 = __builtin_elementwise_fma(wsh2[(4*jb+3)*2+1], t3v, acc23);
            accU = fmaf(su.x, tv0, accU);
            accU = fmaf(su.y, tv1, accU);
            accU = fmaf(su.z, tv2, accU);
            accU = fmaf(su.w, tv3, accU);
        }
        *(float4*)&partial[w * 256 + lane * 4] =
            make_float4(acc01.x, acc01.y, acc23.x, acc23.y);
        pp2[w * 64 + lane] = make_float2(accP, accU);   // one b64 write

        // ======== phase B: act logits + gamma dots (waves 0..3, old hid)
        if (w < 4) {
            float bd = 0.f;
#pragma unroll
            for (int k = 0; k < 4; k++)
                bd = fmaf(whaL[w * 256 + k * 64 + lane], hid[k * 64 + lane], bd);
#pragma unroll
            for (int off = 32; off > 0; off >>= 1) bd += __shfl_down(bd, off);
            if (lane == 0) scal[w] = bd + bscal;
        }
        BAR_LDS(); // s1: partials + pp2 + scal visible; all old-state reads done

        // ---- wave 0 alone: push/pop values (only consumed by stack row 0)
        float pvv = 0.f, uvv = 0.f;
        if (w == 0) {
            float v1 = bhs_r, v2 = bsu_r;
#pragma unroll
            for (int q = 0; q < 8; q++) {
                float2 pq = pp2[q * 64 + lane];        // b64 reads
                v1 += pq.x; v2 += pq.y;
            }
            pvv = fmaxf(v1, 0.f);
            uvv = fmaxf(v2, 0.f);
        }

        // ---- hid reduce (waves 4..7 own one h each)
        if (w >= 4) {
            int h = t - 256;
            float mh = exv;
#pragma unroll
            for (int q = 0; q < 8; q++) mh += partial[q * 256 + h];
            float nh = fmaxf(mh, 0.f);
            hid[h] = nh;
            out[((size_t)ts * BATCH + b) * 256 + h] = nh;
        }

        // ---- softmax -> sharpen (fast transcendentals; all threads redundant)
        float4 sc4 = *(const float4*)scal;             // one b128
        float l0 = sc4.x, l1 = sc4.y, l2 = sc4.z, gv = sc4.w;
        float eg = __expf(gv);
        float g = 1.f + ((gv > 15.f) ? gv : __logf(1.f + eg));
        float m = fmaxf(l0, fmaxf(l1, l2));
        float z = __expf(l0 - m) + __expf(l1 - m) + __expf(l2 - m);
        float lz = __logf(z);
        float s0  = __expf(g * (l0 - m - lz));
        float s1v = __expf(g * (l1 - m - lz));
        float s2v = __expf(g * (l2 - m - lz));
        float S = s0 + s1v + s2v + 1e-16f;
        float rS = __builtin_amdgcn_rcpf(S);
        float p0 = s0 * rS, p1 = s1v * rS, p2 = s2v * rS;

        if (t == 0) {
            int am = 0; float bm = s0;
            if (s1v > bm) { bm = s1v; am = 1; }
            if (s2v > bm) { bm = s2v; am = 2; }
            out[ACTS_OFF + ts * BATCH + b] = (float)am;
        }

        // ---- stack blend fully in registers
        {
            float nv[8];
            float below0 = (w == 0) ? pvv : halo_lo;     // push src for row w*8
            float pop0   = (w == 0) ? uvv : sv[1];       // pop src (row 0 gets u_val)
            nv[0] = fmaf(p0, below0, fmaf(p1, pop0, p2 * sv[0]));
#pragma unroll
            for (int k = 1; k < 7; k++)
                nv[k] = fmaf(p0, sv[k - 1], fmaf(p1, sv[k + 1], p2 * sv[k]));
            nv[7] = fmaf(p0, sv[6], fmaf(p1, halo_hi, p2 * sv[7]));
#pragma unroll
            for (int k = 0; k < 8; k++) sv[k] = nv[k];
        }
        // publish new boundary rows (next step's "old" halo) + tops
        bnd[(w * 2) * 64 + lane] = sv[0];
        bnd[(w * 2 + 1) * 64 + lane] = sv[7];
        if (w == 0) { tops[lane] = sv[0]; tops[64 + lane] = sv[1]; }

        exv = exn;
        BAR_LDS(); // s2: new hid/tops/bnd visible for next step
    }

    // ---- final hid & stack
    if (t < 256) out[HID_OFF + (size_t)b * 256 + t] = hid[t];
#pragma unroll
    for (int k = 0; k < 8; k++)
        out[STACK_OFF + (size_t)b * 4096 + (w * 8 + k) * 64 + lane] = sv[k];
}

// ---------------- launcher ---------------------------------------------------
extern "C" void kernel_launch(void* const* d_in, const int* in_sizes, int n_in,
                              void* d_out, int out_size, void* d_ws, size_t ws_size,
                              hipStream_t stream)
{
    (void)in_sizes; (void)n_in; (void)out_size; (void)ws_size;
    const int*   inputs     = (const int*)d_in[0];
    const float* emb_W      = (const float*)d_in[1];
    const float* W_hh       = (const float*)d_in[2];
    const float* b_hh       = (const float*)d_in[3];
    const float* W_eh       = (const float*)d_in[4];
    const float* b_eh       = (const float*)d_in[5];
    const float* W_ha       = (const float*)d_in[6];
    const float* b_ha       = (const float*)d_in[7];
    const float* W_hg       = (const float*)d_in[8];
    const float* b_hg       = (const float*)d_in[9];
    const float* W_hs       = (const float*)d_in[10];
    const float* b_hs       = (const float*)d_in[11];
    const float* W_sh       = (const float*)d_in[12];
    const float* b_sh       = (const float*)d_in[13];
    const float* W_su       = (const float*)d_in[14];
    const float* b_su       = (const float*)d_in[15];
    const float* empty_elem = (const float*)d_in[16];
    float* out = (float*)d_out;
    float* ws  = (float*)d_ws;

    hipLaunchKernelGGL(prep_kernel, dim3(737), dim3(256), 0, stream,
                       W_hh, b_hh, W_eh, b_eh, W_sh, b_sh, W_hs, W_su, ws);
    hipLaunchKernelGGL(ex_gemm, dim3(1024), dim3(256), 0, stream,
                       inputs, emb_W, ws, out);
    hipLaunchKernelGGL(rnn_scan, dim3(128), dim3(512), 0, stream,
                       ws, W_ha, b_ha, W_hg, b_hg, b_hs, b_su, empty_elem, out);
}

// Round 12
// 571.391 us; speedup vs baseline: 2.2335x; 1.0020x over previous
//
#include <hip/hip_runtime.h>

// EncoderSRNN: T=256 steps, B=128, HDIM=EDIM=256, SSZ=64, SDIM=64, SDEPTH=2, NACT=3
#define T_STEPS 256
#define BATCH 128

// ws float offsets (transposed weights + combined bias)
#define WEHT_OFF 0         // [e][h] 256x256
#define WHHT_OFF 65536     // [e][h] 256x256
#define WSHT_OFF 131072    // [j][h] 128x256
#define WHST_OFF 163840    // [e][s] 256x64
#define WSUT_OFF 180224    // [j][s] 128x64
#define BC_OFF   188416    // bc[h] = b_eh+b_hh+b_sh

#define HID_OFF   8388608
#define STACK_OFF 8421376
#define ACTS_OFF  8945664

typedef __attribute__((ext_vector_type(2))) float f32x2;

// In-loop barrier: LDS-only fence + raw barrier (no vmcnt drain; all cross-wave
// handoffs are DS ops, all global ops in the loop are same-thread ordered).
#define BAR_LDS() do { \
    asm volatile("s_waitcnt lgkmcnt(0)" ::: "memory"); \
    __builtin_amdgcn_s_barrier(); \
} while (0)

// broadcast lane l of v to all lanes via SGPR (VALU pipe, NOT the LDS unit)
__device__ __forceinline__ float rl(float v, int l) {
    return __int_as_float(__builtin_amdgcn_readlane(__float_as_int(v), l));
}

// ---------------- kernel 0: transpose weights into ws, fold biases ----------
__global__ __launch_bounds__(256) void prep_kernel(
    const float* __restrict__ W_hh, const float* __restrict__ b_hh,
    const float* __restrict__ W_eh, const float* __restrict__ b_eh,
    const float* __restrict__ W_sh, const float* __restrict__ b_sh,
    const float* __restrict__ W_hs, const float* __restrict__ W_su,
    float* __restrict__ ws)
{
    int idx = blockIdx.x * 256 + threadIdx.x;
    if (idx < 65536) {                       // W_ehT[e][h] = W_eh[h][e]
        ws[WEHT_OFF + idx] = W_eh[(idx & 255) * 256 + (idx >> 8)];
    } else if (idx < 131072) {               // W_hhT
        int k = idx - 65536;
        ws[WHHT_OFF + k] = W_hh[(k & 255) * 256 + (k >> 8)];
    } else if (idx < 163840) {               // W_shT[j][h] = W_sh[h][j]
        int k = idx - 131072;
        ws[WSHT_OFF + k] = W_sh[(k & 255) * 128 + (k >> 8)];
    } else if (idx < 180224) {               // W_hsT[e][s] = W_hs[s][e]
        int k = idx - 163840;
        ws[WHST_OFF + k] = W_hs[(k & 63) * 256 + (k >> 6)];
    } else if (idx < 188416) {               // W_suT[j][s] = W_su[s][j]
        int k = idx - 180224;
        ws[WSUT_OFF + k] = W_su[(k & 63) * 128 + (k >> 6)];
    } else if (idx < 188672) {
        int k = idx - 188416;
        ws[BC_OFF + k] = b_eh[k] + b_hh[k] + b_sh[k];
    }
}

// ---------------- kernel 1: ex[t,b,h] = emb_W[tok]@W_eh.T + bc  -------------
// v4 = v2's cooperative coalesced staging + v3's readlane consumption.
// v3's defect: per-thread scattered emb gathers (8 random rows, ~900cy L3) at
// each chunk head with the whole readlane chain dependent on them. v4 stages
// the 32x64 emb chunk into LDS with COALESCED loads, then each thread does
// just 8 spread ds_read_b32 (conflict-free, ~120cy) for its rows. DS ops per
// thread per chunk: 2 b128 write + 8 b32 read (v2 had 128 uniform b128 reads).
__global__ __launch_bounds__(256) void ex_gemm(
    const int* __restrict__ tokens, const float* __restrict__ emb_W,
    const float* __restrict__ ws, float* __restrict__ outp)
{
    __shared__ __align__(16) float aT[32 * 68];   // [row][e], stride 68
    __shared__ int tok[32];
    const int t = threadIdx.x, lane = t & 63, rg = t >> 6;
    const int c0 = lane * 4;
    const int R0 = blockIdx.x * 32;
    if (t < 32) tok[t] = tokens[R0 + t];
    __syncthreads();

    f32x2 accA[8], accB[8];
#pragma unroll
    for (int r = 0; r < 8; r++) {
        accA[r] = (f32x2){0.f, 0.f};
        accB[r] = (f32x2){0.f, 0.f};
    }

    for (int e0 = 0; e0 < 256; e0 += 64) {
        {   // cooperative stage: thread t loads row=t>>3, cols seg*8..+8 (coalesced)
            int row = t >> 3, seg = t & 7;
            const float* src = emb_W + (size_t)tok[row] * 256 + e0 + seg * 8;
            float4 v0 = *(const float4*)(src);
            float4 v1 = *(const float4*)(src + 4);
            float* dst = &aT[row * 68 + seg * 8];
            *(float4*)(dst) = v0;          // 16B-aligned (272*row + 32*seg)
            *(float4*)(dst + 4) = v1;
        }
        __syncthreads();
        // spread read: lane l holds col l of each of this wave's 8 rows
        float er[8];
#pragma unroll
        for (int r = 0; r < 8; r++) er[r] = aT[(rg * 8 + r) * 68 + lane];

        const float* wp = ws + WEHT_OFF + (size_t)e0 * 256 + c0;
#pragma unroll
        for (int e = 0; e < 64; e++) {
            float4 wv = *(const float4*)(wp + (size_t)e * 256);  // coalesced, L2
            f32x2 w01 = {wv.x, wv.y}, w23 = {wv.z, wv.w};
#pragma unroll
            for (int r = 0; r < 8; r++) {
                float a = rl(er[r], e);
                f32x2 av = {a, a};
                accA[r] = __builtin_elementwise_fma(w01, av, accA[r]);
                accB[r] = __builtin_elementwise_fma(w23, av, accB[r]);
            }
        }
        __syncthreads();   // all er reads in regs; safe to overwrite aT
    }
    float4 bc4 = *(const float4*)&ws[BC_OFF + c0];
#pragma unroll
    for (int r = 0; r < 8; r++) {
        float4 o;
        o.x = accA[r].x + bc4.x; o.y = accA[r].y + bc4.y;
        o.z = accB[r].x + bc4.z; o.w = accB[r].y + bc4.w;
        *(float4*)&outp[(size_t)(R0 + rg * 8 + r) * 256 + c0] = o;
    }
}

// ---------------- kernel 2: sequential scan, 2 LDS-only barriers/step -------
// UNCHANGED from r11 (431us proven): whh/wsh as pair-aligned f32x2 -> pk_fma,
// 192 pinned regs, slice+readlane state broadcast, packed whs/wsu in LDS.
__attribute__((amdgpu_flat_work_group_size(512, 512)))
__attribute__((amdgpu_waves_per_eu(2, 2)))
__global__ void rnn_scan(
    const float* __restrict__ ws,
    const float* __restrict__ W_ha, const float* __restrict__ b_ha,
    const float* __restrict__ W_hg, const float* __restrict__ b_hg,
    const float* __restrict__ b_hs, const float* __restrict__ b_su,
    const float* __restrict__ empty_elem,
    float* __restrict__ out)
{
    __shared__ __align__(16) float hid[256];
    __shared__ __align__(16) float tops[128];
    __shared__ __align__(16) float partial[8 * 256]; // 8 KB
    __shared__ __align__(16) float2 pp2[8 * 64];     // 4 KB {accP, accU}
    __shared__ __align__(16) float bnd[16 * 64];     // old boundary rows
    __shared__ __align__(16) float wsu_l[8192];      // 32 KB, packed [j>>2][s][j&3]
    __shared__ __align__(16) float whs_l[16384];     // 64 KB, packed [e>>2][s][e&3]
    __shared__ __align__(16) float whaL[1024];       // rows 0-2: W_ha, row 3: W_hg
    __shared__ __align__(16) float scal[4];

    const int t = threadIdx.x, lane = t & 63, w = t >> 6;
    const int b = blockIdx.x;

    // ---- weight registers as aligned pairs (loaded once, liveness-pinned)
    f32x2 whh2[64], wsh2[32];
    {
        const float* base = ws + WHHT_OFF + (size_t)(w * 32) * 256 + lane * 4;
#pragma unroll
        for (int e = 0; e < 32; e++) {
            float4 v = *(const float4*)(base + (size_t)e * 256);
            whh2[2 * e]     = (f32x2){v.x, v.y};
            whh2[2 * e + 1] = (f32x2){v.z, v.w};
        }
        const float* base2 = ws + WSHT_OFF + (size_t)(w * 16) * 256 + lane * 4;
#pragma unroll
        for (int j = 0; j < 16; j++) {
            float4 v = *(const float4*)(base2 + (size_t)j * 256);
            wsh2[2 * j]     = (f32x2){v.x, v.y};
            wsh2[2 * j + 1] = (f32x2){v.z, v.w};
        }
    }
    // pin: opaque 64-bit defs -> not rematerializable, pair-aligned, live on-chip
#pragma unroll
    for (int i = 0; i < 64; i++) asm volatile("" : "+v"(whh2[i]));
#pragma unroll
    for (int i = 0; i < 32; i++) asm volatile("" : "+v"(wsh2[i]));

    // per-role bias registers
    float bscal = 0.f;
    if (lane == 0 && w < 4) bscal = (w < 3) ? b_ha[w] : b_hg[0];
    float bhs_r = 0.f, bsu_r = 0.f;
    if (w == 0) { bhs_r = b_hs[lane]; bsu_r = b_su[lane]; }

    // ---- init state: stack rows in registers, weights + small state in LDS
    const float ev = empty_elem[lane];
    float sv[8];
#pragma unroll
    for (int k = 0; k < 8; k++) sv[k] = ev;
    if (t < 256) hid[t] = 0.f;
    if (t < 128) tops[t] = empty_elem[t & 63];
    bnd[(w * 2) * 64 + lane] = ev;
    bnd[(w * 2 + 1) * 64 + lane] = ev;
    // whs packed quads: src i = e*64+s -> dst (e>>2)*256 + s*4 + (e&3)
    for (int i = t; i < 16384; i += 512)
        whs_l[(i >> 8) * 256 + (i & 63) * 4 + ((i >> 6) & 3)] = ws[WHST_OFF + i];
    for (int i = t; i < 8192; i += 512) {
        int j = i >> 6, s = i & 63;
        wsu_l[(j >> 2) * 256 + s * 4 + (j & 3)] = ws[WSUT_OFF + i];
    }
    for (int i = t; i < 1024; i += 512)
        whaL[i] = (i < 768) ? W_ha[i] : W_hg[i - 768];
    __syncthreads();   // full barrier once (drains init global loads too)

    // combined slice source: lanes 0-31 read this wave's hid slice,
    // lanes 32-47 its tops slice (48-63 duplicate; same-addr broadcast is free)
    const float* slice_ptr = (lane < 32) ? &hid[w * 32 + lane]
                                         : &tops[w * 16 + (lane & 15)];

    // ex double-buffer: preload step 0 (waves 4-7 own hid elem h = t-256)
    float exv = (w >= 4) ? out[(size_t)b * 256 + (t - 256)] : 0.f;

    const float4* whs4 = (const float4*)whs_l;  // [(e>>2)*64 + s]
    const float4* wsu4 = (const float4*)wsu_l;  // [(j>>2)*64 + s]

    for (int ts = 0; ts < T_STEPS; ts++) {
        // prefetch NEXT step's ex (full step of latency cover, no vmcnt at barriers)
        float exn = 0.f;
        if (w >= 4 && ts + 1 < T_STEPS)
            exn = out[((size_t)(ts + 1) * BATCH + b) * 256 + (t - 256)];

        // halo reads: neighbors' OLD boundary rows (published last step)
        float halo_lo = (w == 0) ? 0.f : bnd[((w - 1) * 2 + 1) * 64 + lane]; // row w*8-1
        float halo_hi = (w == 7) ? 0.f : bnd[((w + 1) * 2) * 64 + lane];     // row w*8+8

        // ======== phase A: 1 spread b32 (state) + 8 b128 (whs) + 4 b128 (wsu)
        float slice = *slice_ptr;   // ds_read_b32, full-BW spread
        f32x2 acc01 = (f32x2){0.f, 0.f}, acc23 = (f32x2){0.f, 0.f};
        float accP = 0.f, accU = 0.f;
#pragma unroll
        for (int eb = 0; eb < 8; eb++) {
            float4 sp = whs4[(w * 8 + eb) * 64 + lane];   // spread b128
            float h0 = rl(slice, 4 * eb + 0);
            float h1 = rl(slice, 4 * eb + 1);
            float h2 = rl(slice, 4 * eb + 2);
            float h3 = rl(slice, 4 * eb + 3);
            f32x2 h0v = {h0, h0}, h1v = {h1, h1}, h2v = {h2, h2}, h3v = {h3, h3};
            acc01 = __builtin_elementwise_fma(whh2[(4*eb+0)*2],   h0v, acc01);
            acc23 = __builtin_elementwise_fma(whh2[(4*eb+0)*2+1], h0v, acc23);
            acc01 = __builtin_elementwise_fma(whh2[(4*eb+1)*2],   h1v, acc01);
            acc23 = __builtin_elementwise_fma(whh2[(4*eb+1)*2+1], h1v, acc23);
            acc01 = __builtin_elementwise_fma(whh2[(4*eb+2)*2],   h2v, acc01);
            acc23 = __builtin_elementwise_fma(whh2[(4*eb+2)*2+1], h2v, acc23);
            acc01 = __builtin_elementwise_fma(whh2[(4*eb+3)*2],   h3v, acc01);
            acc23 = __builtin_elementwise_fma(whh2[(4*eb+3)*2+1], h3v, acc23);
            accP = fmaf(sp.x, h0, accP);
            accP = fmaf(sp.y, h1, accP);
            accP = fmaf(sp.z, h2, accP);
            accP = fmaf(sp.w, h3, accP);
        }
#pragma unroll
        for (int jb = 0; jb < 4; jb++) {
            float4 su = wsu4[(w * 4 + jb) * 64 + lane];   // spread b128
            float tv0 = rl(slice, 32 + 4 * jb);
            float tv1 = rl(slice, 32 + 4 * jb + 1);
            float tv2 = rl(slice, 32 + 4 * jb + 2);
            float tv3 = rl(slice, 32 + 4 * jb + 3);
            f32x2 t0v = {tv0, tv0}, t1v = {tv1, tv1}, t2v = {tv2, tv2}, t3v = {tv3, tv3};
            acc01 = __builtin_elementwise_fma(wsh2[(4*jb+0)*2],   t0v, acc01);
            acc23 = __builtin_elementwise_fma(wsh2[(4*jb+0)*2+1], t0v, acc23);
            acc01 = __builtin_elementwise_fma(wsh2[(4*jb+1)*2],   t1v, acc01);
            acc23 = __builtin_elementwise_fma(wsh2[(4*jb+1)*2+1], t1v, acc23);
            acc01 = __builtin_elementwise_fma(wsh2[(4*jb+2)*2],   t2v, acc01);
            acc23 = __builtin_elementwise_fma(wsh2[(4*jb+2)*2+1], t2v, acc23);
            acc01 = __builtin_elementwise_fma(wsh2[(4*jb+3)*2],   t3v, acc01);
            acc23 = __builtin_elementwise_fma(wsh2[(4*jb+3)*2+1], t3v, acc23);
            accU = fmaf(su.x, tv0, accU);
            accU = fmaf(su.y, tv1, accU);
            accU = fmaf(su.z, tv2, accU);
            accU = fmaf(su.w, tv3, accU);
        }
        *(float4*)&partial[w * 256 + lane * 4] =
            make_float4(acc01.x, acc01.y, acc23.x, acc23.y);
        pp2[w * 64 + lane] = make_float2(accP, accU);   // one b64 write

        // ======== phase B: act logits + gamma dots (waves 0..3, old hid)
        if (w < 4) {
            float bd = 0.f;
#pragma unroll
            for (int k = 0; k < 4; k++)
                bd = fmaf(whaL[w * 256 + k * 64 + lane], hid[k * 64 + lane], bd);
#pragma unroll
            for (int off = 32; off > 0; off >>= 1) bd += __shfl_down(bd, off);
            if (lane == 0) scal[w] = bd + bscal;
        }
        BAR_LDS(); // s1: partials + pp2 + scal visible; all old-state reads done

        // ---- wave 0 alone: push/pop values (only consumed by stack row 0)
        float pvv = 0.f, uvv = 0.f;
        if (w == 0) {
            float v1 = bhs_r, v2 = bsu_r;
#pragma unroll
            for (int q = 0; q < 8; q++) {
                float2 pq = pp2[q * 64 + lane];        // b64 reads
                v1 += pq.x; v2 += pq.y;
            }
            pvv = fmaxf(v1, 0.f);
            uvv = fmaxf(v2, 0.f);
        }

        // ---- hid reduce (waves 4..7 own one h each)
        if (w >= 4) {
            int h = t - 256;
            float mh = exv;
#pragma unroll
            for (int q = 0; q < 8; q++) mh += partial[q * 256 + h];
            float nh = fmaxf(mh, 0.f);
            hid[h] = nh;
            out[((size_t)ts * BATCH + b) * 256 + h] = nh;
        }

        // ---- softmax -> sharpen (fast transcendentals; all threads redundant)
        float4 sc4 = *(const float4*)scal;             // one b128
        float l0 = sc4.x, l1 = sc4.y, l2 = sc4.z, gv = sc4.w;
        float eg = __expf(gv);
        float g = 1.f + ((gv > 15.f) ? gv : __logf(1.f + eg));
        float m = fmaxf(l0, fmaxf(l1, l2));
        float z = __expf(l0 - m) + __expf(l1 - m) + __expf(l2 - m);
        float lz = __logf(z);
        float s0  = __expf(g * (l0 - m - lz));
        float s1v = __expf(g * (l1 - m - lz));
        float s2v = __expf(g * (l2 - m - lz));
        float S = s0 + s1v + s2v + 1e-16f;
        float rS = __builtin_amdgcn_rcpf(S);
        float p0 = s0 * rS, p1 = s1v * rS, p2 = s2v * rS;

        if (t == 0) {
            int am = 0; float bm = s0;
            if (s1v > bm) { bm = s1v; am = 1; }
            if (s2v > bm) { bm = s2v; am = 2; }
            out[ACTS_OFF + ts * BATCH + b] = (float)am;
        }

        // ---- stack blend fully in registers
        {
            float nv[8];
            float below0 = (w == 0) ? pvv : halo_lo;     // push src for row w*8
            float pop0   = (w == 0) ? uvv : sv[1];       // pop src (row 0 gets u_val)
            nv[0] = fmaf(p0, below0, fmaf(p1, pop0, p2 * sv[0]));
#pragma unroll
            for (int k = 1; k < 7; k++)
                nv[k] = fmaf(p0, sv[k - 1], fmaf(p1, sv[k + 1], p2 * sv[k]));
            nv[7] = fmaf(p0, sv[6], fmaf(p1, halo_hi, p2 * sv[7]));
#pragma unroll
            for (int k = 0; k < 8; k++) sv[k] = nv[k];
        }
        // publish new boundary rows (next step's "old" halo) + tops
        bnd[(w * 2) * 64 + lane] = sv[0];
        bnd[(w * 2 + 1) * 64 + lane] = sv[7];
        if (w == 0) { tops[lane] = sv[0]; tops[64 + lane] = sv[1]; }

        exv = exn;
        BAR_LDS(); // s2: new hid/tops/bnd visible for next step
    }

    // ---- final hid & stack
    if (t < 256) out[HID_OFF + (size_t)b * 256 + t] = hid[t];
#pragma unroll
    for (int k = 0; k < 8; k++)
        out[STACK_OFF + (size_t)b * 4096 + (w * 8 + k) * 64 + lane] = sv[k];
}

// ---------------- launcher ---------------------------------------------------
extern "C" void kernel_launch(void* const* d_in, const int* in_sizes, int n_in,
                              void* d_out, int out_size, void* d_ws, size_t ws_size,
                              hipStream_t stream)
{
    (void)in_sizes; (void)n_in; (void)out_size; (void)ws_size;
    const int*   inputs     = (const int*)d_in[0];
    const float* emb_W      = (const float*)d_in[1];
    const float* W_hh       = (const float*)d_in[2];
    const float* b_hh       = (const float*)d_in[3];
    const float* W_eh       = (const float*)d_in[4];
    const float* b_eh       = (const float*)d_in[5];
    const float* W_ha       = (const float*)d_in[6];
    const float* b_ha       = (const float*)d_in[7];
    const float* W_hg       = (const float*)d_in[8];
    const float* b_hg       = (const float*)d_in[9];
    const float* W_hs       = (const float*)d_in[10];
    const float* b_hs       = (const float*)d_in[11];
    const float* W_sh       = (const float*)d_in[12];
    const float* b_sh       = (const float*)d_in[13];
    const float* W_su       = (const float*)d_in[14];
    const float* b_su       = (const float*)d_in[15];
    const float* empty_elem = (const float*)d_in[16];
    float* out = (float*)d_out;
    float* ws  = (float*)d_ws;

    hipLaunchKernelGGL(prep_kernel, dim3(737), dim3(256), 0, stream,
                       W_hh, b_hh, W_eh, b_eh, W_sh, b_sh, W_hs, W_su, ws);
    hipLaunchKernelGGL(ex_gemm, dim3(1024), dim3(256), 0, stream,
                       inputs, emb_W, ws, out);
    hipLaunchKernelGGL(rnn_scan, dim3(128), dim3(512), 0, stream,
                       ws, W_ha, b_ha, W_hg, b_hg, b_hs, b_su, empty_elem, out);
}